// Round 1
// baseline (409.695 us; speedup 1.0000x reference)
//
#include <hip/hip_runtime.h>
#include <hip/hip_bf16.h>
#include <stdint.h>

#define NN 4096      // nodes
#define NF 512       // NFEAT = NHEADS*NHID = concat width
#define NH 64        // NHID
#define NCLS 40      // NCLASS
#define NHEADS 8
#define H2C 48       // padded class width (3 MFMA n-chunks)

typedef __attribute__((ext_vector_type(8))) short bh8;
typedef __attribute__((ext_vector_type(4))) float f32x4;

__device__ __forceinline__ unsigned short f2bu(float f) {
    union { float f; unsigned u; } v; v.f = f;
    unsigned r = (v.u + 0x7FFFu + ((v.u >> 16) & 1u)) >> 16;
    return (unsigned short)r;
}
__device__ __forceinline__ float b2f(unsigned short b) {
    union { unsigned u; float f; } v; v.u = ((unsigned)b) << 16;
    return v.f;
}
__device__ __forceinline__ float lrelu(float x) { return fmaxf(x, 0.2f * x); }
__device__ __forceinline__ float elu1(float x) { return x > 0.f ? x : expm1f(x); }

// ---------------- prep kernels ----------------
__global__ void prep_xb_k(const float* __restrict__ x, unsigned short* __restrict__ xb) {
    int idx = blockIdx.x * 256 + threadIdx.x;           // 4096*512 exact
    xb[idx] = f2bu(x[idx]);
}
__global__ void prep_WT_k(const float* __restrict__ Ws, unsigned short* __restrict__ WT) {
    int idx = blockIdx.x * 256 + threadIdx.x;           // c*512 + k, 512*512
    int c = idx >> 9, k = idx & 511;
    WT[idx] = f2bu(Ws[(size_t)(c >> 6) * (NF * NH) + (size_t)k * NH + (c & 63)]);
}
__global__ void prep_WoT_k(const float* __restrict__ Wo, unsigned short* __restrict__ WoT) {
    int idx = blockIdx.x * 256 + threadIdx.x;           // c*512 + k, 48*512
    int c = idx >> 9, k = idx & 511;
    WoT[idx] = f2bu(c < NCLS ? Wo[(size_t)k * NCLS + c] : 0.f);
}
__global__ __launch_bounds__(256) void prep_adj_k(const float* __restrict__ adj,
                                                  uint64_t* __restrict__ adjb) {
    int w = threadIdx.x >> 6, lane = threadIdx.x & 63;
    int i = blockIdx.x * 4 + w;
    const float* row = adj + (size_t)i * NN;
    for (int t = 0; t < 64; ++t) {
        uint64_t msk = __ballot(row[t * 64 + lane] > 0.f);
        if (lane == 0) adjb[(size_t)i * 64 + t] = msk;
    }
}

// ---------------- bf16 MFMA GEMM: H1 = x @ Wcat  (4096x512x512) ----------------
__global__ __launch_bounds__(256) void gemm1_k(const unsigned short* __restrict__ xb,
                                               const unsigned short* __restrict__ WT,
                                               unsigned short* __restrict__ H1b,
                                               float* __restrict__ H1f) {
    __shared__ unsigned short xs[64 * 40];
    __shared__ unsigned short wsm[64 * 40];
    const int tid = threadIdx.x;
    const int w = tid >> 6, lane = tid & 63, r16 = lane & 15, grp = lane >> 4;
    const int i0 = blockIdx.x << 6, c0 = blockIdx.y << 6;
    const int srow = tid >> 2, sseg = tid & 3;
    const unsigned short* xsrc = xb + (size_t)(i0 + srow) * NF + sseg * 8;
    const unsigned short* wsrc = WT + (size_t)(c0 + srow) * NF + sseg * 8;
    f32x4 a0 = {0,0,0,0}, a1 = {0,0,0,0}, a2 = {0,0,0,0}, a3 = {0,0,0,0};
    for (int kb = 0; kb < NF; kb += 32) {
        *(bh8*)(xs + srow * 40 + sseg * 8) = *(const bh8*)(xsrc + kb);
        *(bh8*)(wsm + srow * 40 + sseg * 8) = *(const bh8*)(wsrc + kb);
        __syncthreads();
        bh8 af = *(const bh8*)(xs + (w * 16 + r16) * 40 + grp * 8);
        bh8 b0 = *(const bh8*)(wsm + (r16) * 40 + grp * 8);
        bh8 b1 = *(const bh8*)(wsm + (16 + r16) * 40 + grp * 8);
        bh8 b2 = *(const bh8*)(wsm + (32 + r16) * 40 + grp * 8);
        bh8 b3 = *(const bh8*)(wsm + (48 + r16) * 40 + grp * 8);
        a0 = __builtin_amdgcn_mfma_f32_16x16x32_bf16(af, b0, a0, 0, 0, 0);
        a1 = __builtin_amdgcn_mfma_f32_16x16x32_bf16(af, b1, a1, 0, 0, 0);
        a2 = __builtin_amdgcn_mfma_f32_16x16x32_bf16(af, b2, a2, 0, 0, 0);
        a3 = __builtin_amdgcn_mfma_f32_16x16x32_bf16(af, b3, a3, 0, 0, 0);
        __syncthreads();
    }
#pragma unroll
    for (int r = 0; r < 4; ++r) {
        const int orow = i0 + w * 16 + grp * 4 + r;
        unsigned short* o = H1b + (size_t)orow * NF + c0 + r16;
        float* of = H1f + (size_t)orow * NF + c0 + r16;
        o[0] = f2bu(a0[r]);  o[16] = f2bu(a1[r]);  o[32] = f2bu(a2[r]);  o[48] = f2bu(a3[r]);
        of[0] = a0[r];       of[16] = a1[r];       of[32] = a2[r];       of[48] = a3[r];
    }
}

// ---------------- bf16 MFMA GEMM: H2 = x2 @ W_out (4096x512x48) ----------------
__global__ __launch_bounds__(256) void gemm2_k(const unsigned short* __restrict__ x2b,
                                               const unsigned short* __restrict__ WoT,
                                               unsigned short* __restrict__ H2b,
                                               float* __restrict__ H2f) {
    __shared__ unsigned short xs[64 * 40];
    __shared__ unsigned short wsm[48 * 40];
    const int tid = threadIdx.x;
    const int w = tid >> 6, lane = tid & 63, r16 = lane & 15, grp = lane >> 4;
    const int i0 = blockIdx.x << 6;
    const int srow = tid >> 2, sseg = tid & 3;
    const unsigned short* xsrc = x2b + (size_t)(i0 + srow) * NF + sseg * 8;
    const unsigned short* wsrc = WoT + (size_t)srow * NF + sseg * 8;
    f32x4 a0 = {0,0,0,0}, a1 = {0,0,0,0}, a2 = {0,0,0,0};
    for (int kb = 0; kb < NF; kb += 32) {
        *(bh8*)(xs + srow * 40 + sseg * 8) = *(const bh8*)(xsrc + kb);
        if (tid < 192) *(bh8*)(wsm + srow * 40 + sseg * 8) = *(const bh8*)(wsrc + kb);
        __syncthreads();
        bh8 af = *(const bh8*)(xs + (w * 16 + r16) * 40 + grp * 8);
        bh8 b0 = *(const bh8*)(wsm + (r16) * 40 + grp * 8);
        bh8 b1 = *(const bh8*)(wsm + (16 + r16) * 40 + grp * 8);
        bh8 b2 = *(const bh8*)(wsm + (32 + r16) * 40 + grp * 8);
        a0 = __builtin_amdgcn_mfma_f32_16x16x32_bf16(af, b0, a0, 0, 0, 0);
        a1 = __builtin_amdgcn_mfma_f32_16x16x32_bf16(af, b1, a1, 0, 0, 0);
        a2 = __builtin_amdgcn_mfma_f32_16x16x32_bf16(af, b2, a2, 0, 0, 0);
        __syncthreads();
    }
#pragma unroll
    for (int r = 0; r < 4; ++r) {
        const int orow = i0 + w * 16 + grp * 4 + r;
        unsigned short* o = H2b + (size_t)orow * H2C + r16;
        float* of = H2f + (size_t)orow * H2C + r16;
        o[0] = f2bu(a0[r]);  o[16] = f2bu(a1[r]);  o[32] = f2bu(a2[r]);
        of[0] = a0[r];       of[16] = a1[r];       of[32] = a2[r];
    }
}

// ---------------- bf16 transpose (tiled) ----------------
__global__ void transpose_k(const unsigned short* __restrict__ in,
                            unsigned short* __restrict__ out, int R, int C) {
    __shared__ unsigned short t[32][33];
    int c0 = blockIdx.x * 32, r0 = blockIdx.y * 32;
    int x = threadIdx.x & 31, y = threadIdx.x >> 5;     // 32x8
    for (int k = 0; k < 4; ++k) {
        int r = r0 + y + k * 8, c = c0 + x;
        if (r < R && c < C) t[y + k * 8][x] = in[(size_t)r * C + c];
    }
    __syncthreads();
    for (int k = 0; k < 4; ++k) {
        int c = c0 + y + k * 8, r = r0 + x;
        if (r < R && c < C) out[(size_t)c * R + r] = t[x][y + k * 8];
    }
}

// ---------------- f1/f2 per head (layer 1) ----------------
__global__ __launch_bounds__(512) void fcomp1_k(const float* __restrict__ H1f,
                                                const float* __restrict__ a_s,
                                                float* __restrict__ f1s, float* __restrict__ f2s) {
    int i = blockIdx.x;
    int h = threadIdx.x >> 6, lane = threadIdx.x & 63;
    float hv = H1f[(size_t)i * NF + h * 64 + lane];
    float s1 = hv * a_s[h * 128 + lane];
    float s2 = hv * a_s[h * 128 + 64 + lane];
#pragma unroll
    for (int o = 32; o > 0; o >>= 1) { s1 += __shfl_xor(s1, o); s2 += __shfl_xor(s2, o); }
    if (lane == 0) { f1s[h * NN + i] = s1; f2s[h * NN + i] = s2; }
}

// ---------------- f1/f2 (layer 2) ----------------
__global__ __launch_bounds__(256) void fcomp2_k(const float* __restrict__ H2f,
                                                const float* __restrict__ a_out,
                                                float* __restrict__ f1, float* __restrict__ f2) {
    int w = threadIdx.x >> 6, lane = threadIdx.x & 63;
    int i = blockIdx.x * 4 + w;
    float hv = (lane < H2C) ? H2f[(size_t)i * H2C + lane] : 0.f;
    float a1 = (lane < NCLS) ? a_out[lane] : 0.f;
    float a2 = (lane < NCLS) ? a_out[NCLS + lane] : 0.f;
    float s1 = hv * a1, s2 = hv * a2;
#pragma unroll
    for (int o = 32; o > 0; o >>= 1) { s1 += __shfl_xor(s1, o); s2 += __shfl_xor(s2, o); }
    if (lane == 0) { f1[i] = s1; f2[i] = s2; }
}

// ---------------- max over a vector (per blockIdx row of length n) ----------------
__global__ void fmax_k(const float* __restrict__ v, float* __restrict__ out, int n) {
    __shared__ float red[256];
    int t = threadIdx.x;
    const float* p = v + (size_t)blockIdx.x * n;
    float mx = -1e30f;
    for (int j = t; j < n; j += 256) mx = fmaxf(mx, p[j]);
    red[t] = mx; __syncthreads();
    for (int s = 128; s > 0; s >>= 1) { if (t < s) red[t] = fmaxf(red[t], red[t + s]); __syncthreads(); }
    if (t == 0) out[blockIdx.x] = red[0];
}

// ---------------- fused masked-softmax attention, layer 1 (all 8 heads) ----------------
__global__ __launch_bounds__(512) void attn1_k(const unsigned short* __restrict__ H1t,
                                               const uint64_t* __restrict__ adjb,
                                               const float* __restrict__ f1s,
                                               const float* __restrict__ f2s,
                                               const float* __restrict__ fmax1,
                                               unsigned short* __restrict__ x2b) {
    const int tid = threadIdx.x;
    const int h = tid >> 6;                 // wave = head
    const int lane = tid & 63;
    const int r16 = lane & 15, grp = lane >> 4;
    const int i0 = blockIdx.x << 4;
    const int i = i0 + r16;
    const float f1v = f1s[h * NN + i];
    const float m = lrelu(f1v + fmax1[h]);  // upper bound on lrelu(f1+f2[j])
    const float* f2p = f2s + h * NN;
    const unsigned char* adjB = ((const unsigned char*)adjb) + (size_t)i * 512 + grp;
    const unsigned short* Hb = H1t + ((size_t)(h * 64 + r16)) * NN + grp * 8;
    f32x4 acc0 = {0,0,0,0}, acc1 = {0,0,0,0}, acc2 = {0,0,0,0}, acc3 = {0,0,0,0}, accd = {0,0,0,0};
    const short ov = (r16 == 0) ? (short)0x3F80 : (short)0;
    bh8 ones;
#pragma unroll
    for (int e = 0; e < 8; ++e) ones[e] = ov;
#pragma unroll 2
    for (int jt = 0; jt < 128; ++jt) {
        const int j0 = jt << 5;
        float4 fa = *(const float4*)(f2p + j0 + grp * 8);
        float4 fb = *(const float4*)(f2p + j0 + grp * 8 + 4);
        const unsigned ab = adjB[jt * 4];
        float f2e[8] = {fa.x, fa.y, fa.z, fa.w, fb.x, fb.y, fb.z, fb.w};
        bh8 pa;
#pragma unroll
        for (int e = 0; e < 8; ++e) {
            float t = f1v + f2e[e];
            float s = lrelu(t) - m;
            float p = __expf(s);
            p = ((ab >> e) & 1u) ? p : 0.0f;
            pa[e] = (short)f2bu(p);
        }
        const unsigned short* Hp = Hb + j0;
        bh8 b0 = *(const bh8*)(Hp);
        bh8 b1 = *(const bh8*)(Hp + 16 * NN);
        bh8 b2 = *(const bh8*)(Hp + 32 * NN);
        bh8 b3 = *(const bh8*)(Hp + 48 * NN);
        acc0 = __builtin_amdgcn_mfma_f32_16x16x32_bf16(pa, b0, acc0, 0, 0, 0);
        acc1 = __builtin_amdgcn_mfma_f32_16x16x32_bf16(pa, b1, acc1, 0, 0, 0);
        acc2 = __builtin_amdgcn_mfma_f32_16x16x32_bf16(pa, b2, acc2, 0, 0, 0);
        acc3 = __builtin_amdgcn_mfma_f32_16x16x32_bf16(pa, b3, acc3, 0, 0, 0);
        accd = __builtin_amdgcn_mfma_f32_16x16x32_bf16(pa, ones, accd, 0, 0, 0);
    }
#pragma unroll
    for (int r = 0; r < 4; ++r) {
        const int orow = grp * 4 + r;
        const float den = __shfl(accd[r], lane & 48);
        const float inv = 1.0f / den;
        unsigned short* o = x2b + (size_t)(i0 + orow) * NF + h * 64 + r16;
        o[0]  = f2bu(elu1(acc0[r] * inv));
        o[16] = f2bu(elu1(acc1[r] * inv));
        o[32] = f2bu(elu1(acc2[r] * inv));
        o[48] = f2bu(elu1(acc3[r] * inv));
    }
}

// ---------------- attention layer 2 + elu + log_softmax ----------------
__global__ __launch_bounds__(256) void attn2_k(const unsigned short* __restrict__ H2t,
                                               const uint64_t* __restrict__ adjb,
                                               const float* __restrict__ f1,
                                               const float* __restrict__ f2,
                                               const float* __restrict__ fmax2,
                                               float* __restrict__ out) {
    __shared__ float red[4][16][49];
    const int tid = threadIdx.x;
    const int w = tid >> 6;
    const int lane = tid & 63;
    const int r16 = lane & 15, grp = lane >> 4;
    const int i0 = blockIdx.x << 4;
    const int i = i0 + r16;
    const float f1v = f1[i];
    const float m = lrelu(f1v + fmax2[0]);
    const unsigned char* adjB = ((const unsigned char*)adjb) + (size_t)i * 512 + grp;
    const unsigned short* Hb = H2t + (size_t)r16 * NN + grp * 8;
    f32x4 acc0 = {0,0,0,0}, acc1 = {0,0,0,0}, acc2 = {0,0,0,0}, accd = {0,0,0,0};
    const short ov = (r16 == 0) ? (short)0x3F80 : (short)0;
    bh8 ones;
#pragma unroll
    for (int e = 0; e < 8; ++e) ones[e] = ov;
    for (int jt = w; jt < 128; jt += 4) {
        const int j0 = jt << 5;
        float4 fa = *(const float4*)(f2 + j0 + grp * 8);
        float4 fb = *(const float4*)(f2 + j0 + grp * 8 + 4);
        const unsigned ab = adjB[jt * 4];
        float f2e[8] = {fa.x, fa.y, fa.z, fa.w, fb.x, fb.y, fb.z, fb.w};
        bh8 pa;
#pragma unroll
        for (int e = 0; e < 8; ++e) {
            float t = f1v + f2e[e];
            float s = lrelu(t) - m;
            float p = __expf(s);
            p = ((ab >> e) & 1u) ? p : 0.0f;
            pa[e] = (short)f2bu(p);
        }
        bh8 b0 = *(const bh8*)(Hb + j0);
        bh8 b1 = *(const bh8*)(Hb + j0 + 16 * NN);
        bh8 b2 = *(const bh8*)(Hb + j0 + 32 * NN);
        acc0 = __builtin_amdgcn_mfma_f32_16x16x32_bf16(pa, b0, acc0, 0, 0, 0);
        acc1 = __builtin_amdgcn_mfma_f32_16x16x32_bf16(pa, b1, acc1, 0, 0, 0);
        acc2 = __builtin_amdgcn_mfma_f32_16x16x32_bf16(pa, b2, acc2, 0, 0, 0);
        accd = __builtin_amdgcn_mfma_f32_16x16x32_bf16(pa, ones, accd, 0, 0, 0);
    }
#pragma unroll
    for (int r = 0; r < 4; ++r) {
        const int row = grp * 4 + r;
        red[w][row][r16] = acc0[r];
        red[w][row][16 + r16] = acc1[r];
        red[w][row][32 + r16] = acc2[r];
        if (r16 == 0) red[w][row][48] = accd[r];
    }
    __syncthreads();
    for (int idx = tid; idx < 16 * 49; idx += 256) {
        int row = idx / 49, c = idx % 49;
        red[0][row][c] = red[0][row][c] + red[1][row][c] + red[2][row][c] + red[3][row][c];
    }
    __syncthreads();
    if (tid < 16) {
        const int row = tid;
        const float inv = 1.0f / red[0][row][48];
        float mx = -1e30f;
        for (int c = 0; c < NCLS; ++c) {
            float v = elu1(red[0][row][c] * inv);
            red[0][row][c] = v;
            mx = fmaxf(mx, v);
        }
        float s = 0.f;
        for (int c = 0; c < NCLS; ++c) s += __expf(red[0][row][c] - mx);
        const float lse = mx + logf(s);
        float* op = out + (size_t)(i0 + row) * NCLS;
        for (int c = 0; c < NCLS; ++c) op[c] = red[0][row][c] - lse;
    }
}

// ---------------- workspace layout (bytes) ----------------
#define OFF_XB   0ULL           // 4096*512*2
#define OFF_WT   4194304ULL     // 512*512*2
#define OFF_H1B  4718592ULL     // 4096*512*2
#define OFF_H1T  8912896ULL     // 512*4096*2
#define OFF_H1F  13107200ULL    // 4096*512*4
#define OFF_X2B  21495808ULL    // 4096*512*2
#define OFF_WOT  25690112ULL    // 48*512*2
#define OFF_H2B  25739264ULL    // 4096*48*2 (pad)
#define OFF_H2T  26132480ULL    // 48*4096*2 (pad)
#define OFF_H2F  26525696ULL    // 4096*48*4
#define OFF_F1S  27312128ULL    // 8*4096*4
#define OFF_F2S  27443200ULL    // 8*4096*4
#define OFF_F12  27574272ULL    // 4096*4
#define OFF_F22  27590656ULL    // 4096*4
#define OFF_FM1  27607040ULL    // 8*4 (pad 256)
#define OFF_FM2  27607296ULL    // 4 (pad 256)
#define OFF_ADJ  27607552ULL    // 4096*64*8

extern "C" void kernel_launch(void* const* d_in, const int* in_sizes, int n_in,
                              void* d_out, int out_size, void* d_ws, size_t ws_size,
                              hipStream_t stream) {
    const float* x     = (const float*)d_in[0];
    const float* adj   = (const float*)d_in[1];
    const float* Ws    = (const float*)d_in[2];
    const float* a_s   = (const float*)d_in[3];
    const float* W_out = (const float*)d_in[4];
    const float* a_out = (const float*)d_in[5];
    float* out = (float*)d_out;
    char* w = (char*)d_ws;

    unsigned short* xb  = (unsigned short*)(w + OFF_XB);
    unsigned short* WT  = (unsigned short*)(w + OFF_WT);
    unsigned short* H1b = (unsigned short*)(w + OFF_H1B);
    unsigned short* H1t = (unsigned short*)(w + OFF_H1T);
    float*          H1f = (float*)(w + OFF_H1F);
    unsigned short* x2b = (unsigned short*)(w + OFF_X2B);
    unsigned short* WoT = (unsigned short*)(w + OFF_WOT);
    unsigned short* H2b = (unsigned short*)(w + OFF_H2B);
    unsigned short* H2t = (unsigned short*)(w + OFF_H2T);
    float*          H2f = (float*)(w + OFF_H2F);
    float* f1s = (float*)(w + OFF_F1S);
    float* f2s = (float*)(w + OFF_F2S);
    float* f12 = (float*)(w + OFF_F12);
    float* f22 = (float*)(w + OFF_F22);
    float* FM1 = (float*)(w + OFF_FM1);
    float* FM2 = (float*)(w + OFF_FM2);
    uint64_t* adjb = (uint64_t*)(w + OFF_ADJ);

    prep_xb_k<<<8192, 256, 0, stream>>>(x, xb);
    prep_WT_k<<<1024, 256, 0, stream>>>(Ws, WT);
    prep_WoT_k<<<96, 256, 0, stream>>>(W_out, WoT);
    prep_adj_k<<<1024, 256, 0, stream>>>(adj, adjb);

    gemm1_k<<<dim3(64, 8), 256, 0, stream>>>(xb, WT, H1b, H1f);
    transpose_k<<<dim3(16, 128), 256, 0, stream>>>(H1b, H1t, NN, NF);
    fcomp1_k<<<4096, 512, 0, stream>>>(H1f, a_s, f1s, f2s);
    fmax_k<<<8, 256, 0, stream>>>(f2s, FM1, NN);
    attn1_k<<<256, 512, 0, stream>>>(H1t, adjb, f1s, f2s, FM1, x2b);

    gemm2_k<<<64, 256, 0, stream>>>(x2b, WoT, H2b, H2f);
    transpose_k<<<dim3(2, 128), 256, 0, stream>>>(H2b, H2t, NN, H2C);
    fcomp2_k<<<1024, 256, 0, stream>>>(H2f, a_out, f12, f22);
    fmax_k<<<1, 256, 0, stream>>>(f22, FM2, NN);
    attn2_k<<<256, 256, 0, stream>>>(H2t, adjb, f12, f22, FM2, out);
}

// Round 2
// 317.182 us; speedup vs baseline: 1.2917x; 1.2917x over previous
//
#include <hip/hip_runtime.h>
#include <hip/hip_bf16.h>
#include <stdint.h>

#define NN 4096      // nodes
#define NF 512       // NFEAT = NHEADS*NHID
#define NH 64        // NHID
#define NCLS 40      // NCLASS
#define NHEADS 8
#define H2C 48       // padded class width (3 MFMA n-chunks)
#define LOG2E 1.4426950408889634f

typedef __attribute__((ext_vector_type(8))) short bh8;
typedef __attribute__((ext_vector_type(4))) float f32x4;
typedef unsigned short ushort_t;

__device__ __forceinline__ unsigned short f2bu(float f) {
    union { float f; unsigned u; } v; v.f = f;
    unsigned r = (v.u + 0x7FFFu + ((v.u >> 16) & 1u)) >> 16;
    return (unsigned short)r;
}
__device__ __forceinline__ float lrelu(float x) { return fmaxf(x, 0.2f * x); }
__device__ __forceinline__ float elu1(float x) { return x > 0.f ? x : expm1f(x); }

// score in log2 domain: p = exp2(lrelu(f1L+f2L) - mL), masked
__device__ __forceinline__ float score1(float f2e, float f1v, float mL, unsigned ab, int e) {
    float t = f1v + f2e;
    float s = fmaxf(t, 0.2f * t) - mL;
    float p;
    asm("v_exp_f32 %0, %1" : "=v"(p) : "v"(s));
    return (ab & (1u << e)) ? p : 0.0f;
}

// ---------------- prep kernels ----------------
__global__ void prep_xb_k(const float* __restrict__ x, unsigned short* __restrict__ xb) {
    int idx = blockIdx.x * 256 + threadIdx.x;
    xb[idx] = f2bu(x[idx]);
}
__global__ void prep_WT_k(const float* __restrict__ Ws, unsigned short* __restrict__ WT) {
    int idx = blockIdx.x * 256 + threadIdx.x;           // c*512 + k
    int c = idx >> 9, k = idx & 511;
    WT[idx] = f2bu(Ws[(size_t)(c >> 6) * (NF * NH) + (size_t)k * NH + (c & 63)]);
}
__global__ void prep_WoT_k(const float* __restrict__ Wo, unsigned short* __restrict__ WoT) {
    int idx = blockIdx.x * 256 + threadIdx.x;           // c*512 + k, 48*512
    int c = idx >> 9, k = idx & 511;
    WoT[idx] = f2bu(c < NCLS ? Wo[(size_t)k * NCLS + c] : 0.f);
}
__global__ __launch_bounds__(256) void prep_adj_k(const float* __restrict__ adj,
                                                  uint64_t* __restrict__ adjb) {
    int w = threadIdx.x >> 6, lane = threadIdx.x & 63;
    int i = blockIdx.x * 4 + w;
    const float* row = adj + (size_t)i * NN;
    for (int t = 0; t < 64; ++t) {
        uint64_t msk = __ballot(row[t * 64 + lane] > 0.f);
        if (lane == 0) adjb[(size_t)i * 64 + t] = msk;
    }
}

// ---------------- GEMM1: H1 = x @ Wcat  + f1/f2 epilogue ----------------
__global__ __launch_bounds__(256) void gemm1_k(const unsigned short* __restrict__ xb,
                                               const unsigned short* __restrict__ WT,
                                               const float* __restrict__ a_s,
                                               unsigned short* __restrict__ H1b,
                                               float* __restrict__ f1L,
                                               float* __restrict__ f2L) {
    __shared__ unsigned short xs[64 * 40];
    __shared__ unsigned short wsm[64 * 40];
    const int tid = threadIdx.x;
    const int w = tid >> 6, lane = tid & 63, r16 = lane & 15, grp = lane >> 4;
    const int i0 = blockIdx.x << 6, h = blockIdx.y, c0 = h << 6;
    const int srow = tid >> 2, sseg = tid & 3;
    const unsigned short* xsrc = xb + (size_t)(i0 + srow) * NF + sseg * 8;
    const unsigned short* wsrc = WT + (size_t)(c0 + srow) * NF + sseg * 8;
    f32x4 a0 = {0,0,0,0}, a1 = {0,0,0,0}, a2 = {0,0,0,0}, a3 = {0,0,0,0};
    for (int kb = 0; kb < NF; kb += 32) {
        *(bh8*)(xs + srow * 40 + sseg * 8) = *(const bh8*)(xsrc + kb);
        *(bh8*)(wsm + srow * 40 + sseg * 8) = *(const bh8*)(wsrc + kb);
        __syncthreads();
        bh8 af = *(const bh8*)(xs + (w * 16 + r16) * 40 + grp * 8);
        bh8 b0 = *(const bh8*)(wsm + (r16) * 40 + grp * 8);
        bh8 b1 = *(const bh8*)(wsm + (16 + r16) * 40 + grp * 8);
        bh8 b2 = *(const bh8*)(wsm + (32 + r16) * 40 + grp * 8);
        bh8 b3 = *(const bh8*)(wsm + (48 + r16) * 40 + grp * 8);
        a0 = __builtin_amdgcn_mfma_f32_16x16x32_bf16(af, b0, a0, 0, 0, 0);
        a1 = __builtin_amdgcn_mfma_f32_16x16x32_bf16(af, b1, a1, 0, 0, 0);
        a2 = __builtin_amdgcn_mfma_f32_16x16x32_bf16(af, b2, a2, 0, 0, 0);
        a3 = __builtin_amdgcn_mfma_f32_16x16x32_bf16(af, b3, a3, 0, 0, 0);
        __syncthreads();
    }
    // a-vector pieces for this lane's 4 columns
    const float* ap = a_s + h * 128;
    float a1v[4], a2v[4];
#pragma unroll
    for (int n = 0; n < 4; ++n) { a1v[n] = ap[r16 + 16 * n]; a2v[n] = ap[64 + r16 + 16 * n]; }
#pragma unroll
    for (int r = 0; r < 4; ++r) {
        const int orow = i0 + w * 16 + grp * 4 + r;
        unsigned short* o = H1b + (size_t)orow * NF + c0 + r16;
        o[0] = f2bu(a0[r]);  o[16] = f2bu(a1[r]);  o[32] = f2bu(a2[r]);  o[48] = f2bu(a3[r]);
        float s1 = a0[r] * a1v[0] + a1[r] * a1v[1] + a2[r] * a1v[2] + a3[r] * a1v[3];
        float s2 = a0[r] * a2v[0] + a1[r] * a2v[1] + a2[r] * a2v[2] + a3[r] * a2v[3];
#pragma unroll
        for (int o2 = 1; o2 < 16; o2 <<= 1) { s1 += __shfl_xor(s1, o2); s2 += __shfl_xor(s2, o2); }
        if (r16 == 0) { f1L[h * NN + orow] = s1 * LOG2E; f2L[h * NN + orow] = s2 * LOG2E; }
    }
}

// ---------------- GEMM2: H2 = x2 @ W_out + f epilogue ----------------
__global__ __launch_bounds__(256) void gemm2_k(const unsigned short* __restrict__ x2b,
                                               const unsigned short* __restrict__ WoT,
                                               const float* __restrict__ a_out,
                                               unsigned short* __restrict__ H2b,
                                               float* __restrict__ f12L,
                                               float* __restrict__ f22L) {
    __shared__ unsigned short xs[64 * 40];
    __shared__ unsigned short wsm[48 * 40];
    const int tid = threadIdx.x;
    const int w = tid >> 6, lane = tid & 63, r16 = lane & 15, grp = lane >> 4;
    const int i0 = blockIdx.x << 6;
    const int srow = tid >> 2, sseg = tid & 3;
    const unsigned short* xsrc = x2b + (size_t)(i0 + srow) * NF + sseg * 8;
    const unsigned short* wsrc = WoT + (size_t)srow * NF + sseg * 8;
    f32x4 a0 = {0,0,0,0}, a1 = {0,0,0,0}, a2 = {0,0,0,0};
    for (int kb = 0; kb < NF; kb += 32) {
        *(bh8*)(xs + srow * 40 + sseg * 8) = *(const bh8*)(xsrc + kb);
        if (tid < 192) *(bh8*)(wsm + srow * 40 + sseg * 8) = *(const bh8*)(wsrc + kb);
        __syncthreads();
        bh8 af = *(const bh8*)(xs + (w * 16 + r16) * 40 + grp * 8);
        bh8 b0 = *(const bh8*)(wsm + (r16) * 40 + grp * 8);
        bh8 b1 = *(const bh8*)(wsm + (16 + r16) * 40 + grp * 8);
        bh8 b2 = *(const bh8*)(wsm + (32 + r16) * 40 + grp * 8);
        a0 = __builtin_amdgcn_mfma_f32_16x16x32_bf16(af, b0, a0, 0, 0, 0);
        a1 = __builtin_amdgcn_mfma_f32_16x16x32_bf16(af, b1, a1, 0, 0, 0);
        a2 = __builtin_amdgcn_mfma_f32_16x16x32_bf16(af, b2, a2, 0, 0, 0);
        __syncthreads();
    }
    float a1v[3], a2v[3];
#pragma unroll
    for (int n = 0; n < 3; ++n) {
        int col = r16 + 16 * n;
        a1v[n] = col < NCLS ? a_out[col] : 0.f;
        a2v[n] = col < NCLS ? a_out[NCLS + col] : 0.f;
    }
#pragma unroll
    for (int r = 0; r < 4; ++r) {
        const int orow = i0 + w * 16 + grp * 4 + r;
        unsigned short* o = H2b + (size_t)orow * H2C + r16;
        o[0] = f2bu(a0[r]);  o[16] = f2bu(a1[r]);  o[32] = f2bu(a2[r]);
        float s1 = a0[r] * a1v[0] + a1[r] * a1v[1] + a2[r] * a1v[2];
        float s2 = a0[r] * a2v[0] + a1[r] * a2v[1] + a2[r] * a2v[2];
#pragma unroll
        for (int o2 = 1; o2 < 16; o2 <<= 1) { s1 += __shfl_xor(s1, o2); s2 += __shfl_xor(s2, o2); }
        if (r16 == 0) { f12L[orow] = s1 * LOG2E; f22L[orow] = s2 * LOG2E; }
    }
}

// ---------------- repack H1b -> B-panels Bp1[h][jt][f][lane][e] ----------------
__global__ __launch_bounds__(256) void repack1_k(const unsigned short* __restrict__ H1b,
                                                 unsigned short* __restrict__ Bp1) {
    __shared__ unsigned short t2[32][72];
    const int jt = blockIdx.x, h = blockIdx.y, tid = threadIdx.x;
    const int tr = tid >> 3, tc = tid & 7;
    *(bh8*)(&t2[tr][tc * 8]) = *(const bh8*)(H1b + (size_t)(jt * 32 + tr) * NF + h * 64 + tc * 8);
    __syncthreads();
    const int f = tid >> 6, l = tid & 63;
    unsigned short tmp[8];
#pragma unroll
    for (int e = 0; e < 8; ++e) tmp[e] = t2[(l >> 4) * 8 + e][f * 16 + (l & 15)];
    *(bh8*)(Bp1 + ((size_t)(h * 128 + jt) * 2048) + f * 512 + l * 8) = *(bh8*)tmp;
}

// ---------------- repack H2b -> Bp2[jt][f<3][lane][e] ----------------
__global__ __launch_bounds__(256) void repack2_k(const unsigned short* __restrict__ H2b,
                                                 unsigned short* __restrict__ Bp2) {
    __shared__ unsigned short t2[32][56];
    const int jt = blockIdx.x, tid = threadIdx.x;
    const int tr = tid >> 3, tc = tid & 7;
    if (tc < 6)
        *(bh8*)(&t2[tr][tc * 8]) = *(const bh8*)(H2b + (size_t)(jt * 32 + tr) * H2C + tc * 8);
    __syncthreads();
    const int f = tid >> 6, l = tid & 63;
    if (f < 3) {
        unsigned short tmp[8];
#pragma unroll
        for (int e = 0; e < 8; ++e) tmp[e] = t2[(l >> 4) * 8 + e][f * 16 + (l & 15)];
        *(bh8*)(Bp2 + (size_t)jt * 1536 + f * 512 + l * 8) = *(bh8*)tmp;
    }
}

// ---------------- max over rows ----------------
__global__ void fmax_k(const float* __restrict__ v, float* __restrict__ out, int n) {
    __shared__ float red[256];
    int t = threadIdx.x;
    const float* p = v + (size_t)blockIdx.x * n;
    float mx = -1e30f;
    for (int j = t; j < n; j += 256) mx = fmaxf(mx, p[j]);
    red[t] = mx; __syncthreads();
    for (int s = 128; s > 0; s >>= 1) { if (t < s) red[t] = fmaxf(red[t], red[t + s]); __syncthreads(); }
    if (t == 0) out[blockIdx.x] = red[0];
}

// ---------------- attn layer 1: block = 128 rows x 1 head, LDS-shared B ----------------
__global__ __launch_bounds__(512) void attn1_k(const unsigned short* __restrict__ Bp1,
                                               const uint64_t* __restrict__ adjb,
                                               const float* __restrict__ f1L,
                                               const float* __restrict__ f2L,
                                               const float* __restrict__ FM1,
                                               unsigned short* __restrict__ x2b) {
    __shared__ unsigned short lds[2][2048];
    const int tid = threadIdx.x, w = tid >> 6, lane = tid & 63;
    const int r16 = lane & 15, grp = lane >> 4;
    const int h = blockIdx.y;
    const int i0 = blockIdx.x * 128 + w * 16;
    const int i = i0 + r16;
    const float f1v = f1L[h * NN + i];
    const float mL = lrelu(f1v + FM1[h]);
    const float* f2p = f2L + h * NN;
    const unsigned char* adjB = ((const unsigned char*)adjb) + (size_t)i * 512 + grp;
    const unsigned short* Bbase = Bp1 + (size_t)h * 128 * 2048;
    f32x4 acc0 = {0,0,0,0}, acc1 = {0,0,0,0}, acc2 = {0,0,0,0}, acc3 = {0,0,0,0}, accd = {0,0,0,0};
    const short ov = (r16 == 0) ? (short)0x3F80 : (short)0;
    bh8 ones;
#pragma unroll
    for (int e = 0; e < 8; ++e) ones[e] = ov;
    // prologue: stage jt=0
    bh8 stg;
    if (w < 4) {
        stg = *(const bh8*)(Bbase + w * 512 + lane * 8);
        *(bh8*)(&lds[0][w * 512 + lane * 8]) = stg;
    }
    __syncthreads();
    for (int jt = 0; jt < 128; ++jt) {
        const int cur = jt & 1;
        if (w < 4 && jt < 127)
            stg = *(const bh8*)(Bbase + (size_t)(jt + 1) * 2048 + w * 512 + lane * 8);
        const int j0 = jt << 5;
        float4 fa = *(const float4*)(f2p + j0 + grp * 8);
        float4 fb = *(const float4*)(f2p + j0 + grp * 8 + 4);
        const unsigned ab = adjB[jt * 4];
        float fe[8] = {fa.x, fa.y, fa.z, fa.w, fb.x, fb.y, fb.z, fb.w};
        union { bh8 v; unsigned u[4]; } pk;
#pragma unroll
        for (int e2 = 0; e2 < 4; ++e2) {
            float p0 = score1(fe[2 * e2], f1v, mL, ab, 2 * e2);
            float p1 = score1(fe[2 * e2 + 1], f1v, mL, ab, 2 * e2 + 1);
            pk.u[e2] = (__builtin_bit_cast(unsigned, p0) >> 16) |
                       (__builtin_bit_cast(unsigned, p1) & 0xFFFF0000u);
        }
        bh8 b0 = *(const bh8*)(&lds[cur][0 * 512 + lane * 8]);
        bh8 b1 = *(const bh8*)(&lds[cur][1 * 512 + lane * 8]);
        bh8 b2 = *(const bh8*)(&lds[cur][2 * 512 + lane * 8]);
        bh8 b3 = *(const bh8*)(&lds[cur][3 * 512 + lane * 8]);
        acc0 = __builtin_amdgcn_mfma_f32_16x16x32_bf16(pk.v, b0, acc0, 0, 0, 0);
        acc1 = __builtin_amdgcn_mfma_f32_16x16x32_bf16(pk.v, b1, acc1, 0, 0, 0);
        acc2 = __builtin_amdgcn_mfma_f32_16x16x32_bf16(pk.v, b2, acc2, 0, 0, 0);
        acc3 = __builtin_amdgcn_mfma_f32_16x16x32_bf16(pk.v, b3, acc3, 0, 0, 0);
        accd = __builtin_amdgcn_mfma_f32_16x16x32_bf16(pk.v, ones, accd, 0, 0, 0);
        if (w < 4 && jt < 127)
            *(bh8*)(&lds[cur ^ 1][w * 512 + lane * 8]) = stg;
        __syncthreads();
    }
#pragma unroll
    for (int r = 0; r < 4; ++r) {
        const float den = __shfl(accd[r], lane & 48);
        const float inv = 1.0f / den;
        unsigned short* o = x2b + (size_t)(i0 + grp * 4 + r) * NF + h * 64 + r16;
        o[0]  = f2bu(elu1(acc0[r] * inv));
        o[16] = f2bu(elu1(acc1[r] * inv));
        o[32] = f2bu(elu1(acc2[r] * inv));
        o[48] = f2bu(elu1(acc3[r] * inv));
    }
}

// ---------------- attn layer 2 partial: grid (32 i-blocks, 16 j-chunks) ----------------
__global__ __launch_bounds__(512) void attn2_k(const unsigned short* __restrict__ Bp2,
                                               const uint64_t* __restrict__ adjb,
                                               const float* __restrict__ f12L,
                                               const float* __restrict__ f22L,
                                               const float* __restrict__ FM2,
                                               float* __restrict__ Pa2) {
    __shared__ unsigned short lds[2][1536];
    const int tid = threadIdx.x, w = tid >> 6, lane = tid & 63;
    const int r16 = lane & 15, grp = lane >> 4;
    const int ch = blockIdx.y;
    const int i0 = blockIdx.x * 128 + w * 16;
    const int i = i0 + r16;
    const float f1v = f12L[i];
    const float mL = lrelu(f1v + FM2[0]);
    const unsigned char* adjB = ((const unsigned char*)adjb) + (size_t)i * 512 + grp;
    f32x4 acc0 = {0,0,0,0}, acc1 = {0,0,0,0}, acc2 = {0,0,0,0}, accd = {0,0,0,0};
    const short ov = (r16 == 0) ? (short)0x3F80 : (short)0;
    bh8 ones;
#pragma unroll
    for (int e = 0; e < 8; ++e) ones[e] = ov;
    const int jt0 = ch * 8;
    bh8 stg;
    if (w < 3) {
        stg = *(const bh8*)(Bp2 + (size_t)jt0 * 1536 + w * 512 + lane * 8);
        *(bh8*)(&lds[0][w * 512 + lane * 8]) = stg;
    }
    __syncthreads();
    for (int t = 0; t < 8; ++t) {
        const int jt = jt0 + t;
        const int cur = t & 1;
        if (w < 3 && t < 7)
            stg = *(const bh8*)(Bp2 + (size_t)(jt + 1) * 1536 + w * 512 + lane * 8);
        const int j0 = jt << 5;
        float4 fa = *(const float4*)(f22L + j0 + grp * 8);
        float4 fb = *(const float4*)(f22L + j0 + grp * 8 + 4);
        const unsigned ab = adjB[jt * 4];
        float fe[8] = {fa.x, fa.y, fa.z, fa.w, fb.x, fb.y, fb.z, fb.w};
        union { bh8 v; unsigned u[4]; } pk;
#pragma unroll
        for (int e2 = 0; e2 < 4; ++e2) {
            float p0 = score1(fe[2 * e2], f1v, mL, ab, 2 * e2);
            float p1 = score1(fe[2 * e2 + 1], f1v, mL, ab, 2 * e2 + 1);
            pk.u[e2] = (__builtin_bit_cast(unsigned, p0) >> 16) |
                       (__builtin_bit_cast(unsigned, p1) & 0xFFFF0000u);
        }
        bh8 b0 = *(const bh8*)(&lds[cur][0 * 512 + lane * 8]);
        bh8 b1 = *(const bh8*)(&lds[cur][1 * 512 + lane * 8]);
        bh8 b2 = *(const bh8*)(&lds[cur][2 * 512 + lane * 8]);
        acc0 = __builtin_amdgcn_mfma_f32_16x16x32_bf16(pk.v, b0, acc0, 0, 0, 0);
        acc1 = __builtin_amdgcn_mfma_f32_16x16x32_bf16(pk.v, b1, acc1, 0, 0, 0);
        acc2 = __builtin_amdgcn_mfma_f32_16x16x32_bf16(pk.v, b2, acc2, 0, 0, 0);
        accd = __builtin_amdgcn_mfma_f32_16x16x32_bf16(pk.v, ones, accd, 0, 0, 0);
        if (w < 3 && t < 7)
            *(bh8*)(&lds[cur ^ 1][w * 512 + lane * 8]) = stg;
        __syncthreads();
    }
#pragma unroll
    for (int r = 0; r < 4; ++r) {
        const int row = i0 + grp * 4 + r;
        float* prow = Pa2 + ((size_t)ch * NN + row) * 52;
        prow[r16] = acc0[r];
        prow[16 + r16] = acc1[r];
        prow[32 + r16] = acc2[r];
        if (r16 == 0) prow[48] = accd[r];
    }
}

// ---------------- attn2 finish: reduce chunks, elu, log_softmax ----------------
__global__ __launch_bounds__(256) void attn2fin_k(const float* __restrict__ Pa2,
                                                  float* __restrict__ out) {
    const int tid = threadIdx.x;
    const int row = blockIdx.x * 4 + (tid >> 6);
    const int lane = tid & 63;
    float s = 0.f;
    if (lane < 49) {
#pragma unroll
        for (int c = 0; c < 16; ++c) s += Pa2[((size_t)c * NN + row) * 52 + lane];
    }
    const float den = __shfl(s, 48);
    const float inv = 1.0f / den;
    float v = (lane < NCLS) ? elu1(s * inv) : -3.0e38f;
    float mx = v;
#pragma unroll
    for (int o = 1; o < 64; o <<= 1) mx = fmaxf(mx, __shfl_xor(mx, o));
    float ex = (lane < NCLS) ? __expf(v - mx) : 0.f;
#pragma unroll
    for (int o = 1; o < 64; o <<= 1) ex += __shfl_xor(ex, o);
    const float lse = mx + logf(ex);
    if (lane < NCLS) out[(size_t)row * NCLS + lane] = v - lse;
}

// ---------------- workspace layout (bytes) ----------------
#define OFF_XB   0ULL           // 4096*512*2 = 4194304
#define OFF_WT   4194304ULL     // 512*512*2  = 524288
#define OFF_WOT  4718592ULL     // 48*512*2   = 49152
#define OFF_H1B  4767744ULL     // 4096*512*2 = 4194304
#define OFF_BP1  8962048ULL     // 8*128*2048*2 = 4194304
#define OFF_X2B  13156352ULL    // 4096*512*2 = 4194304
#define OFF_H2B  17350656ULL    // 4096*48*2 = 393216
#define OFF_BP2  17743872ULL    // 128*1536*2 = 393216
#define OFF_F1L  18137088ULL    // 8*4096*4 = 131072
#define OFF_F2L  18268160ULL    // 131072
#define OFF_F12  18399232ULL    // 16384
#define OFF_F22  18415616ULL    // 16384
#define OFF_FM1  18432000ULL    // 256
#define OFF_FM2  18432256ULL    // 256
#define OFF_ADJ  18432512ULL    // 4096*64*8 = 2097152
#define OFF_PA2  20529664ULL    // 16*4096*52*4 = 13631488  -> end 34161152

extern "C" void kernel_launch(void* const* d_in, const int* in_sizes, int n_in,
                              void* d_out, int out_size, void* d_ws, size_t ws_size,
                              hipStream_t stream) {
    const float* x     = (const float*)d_in[0];
    const float* adj   = (const float*)d_in[1];
    const float* Ws    = (const float*)d_in[2];
    const float* a_s   = (const float*)d_in[3];
    const float* W_out = (const float*)d_in[4];
    const float* a_out = (const float*)d_in[5];
    float* out = (float*)d_out;
    char* w = (char*)d_ws;

    unsigned short* xb  = (unsigned short*)(w + OFF_XB);
    unsigned short* WT  = (unsigned short*)(w + OFF_WT);
    unsigned short* WoT = (unsigned short*)(w + OFF_WOT);
    unsigned short* H1b = (unsigned short*)(w + OFF_H1B);
    unsigned short* Bp1 = (unsigned short*)(w + OFF_BP1);
    unsigned short* x2b = (unsigned short*)(w + OFF_X2B);
    unsigned short* H2b = (unsigned short*)(w + OFF_H2B);
    unsigned short* Bp2 = (unsigned short*)(w + OFF_BP2);
    float* f1L = (float*)(w + OFF_F1L);
    float* f2L = (float*)(w + OFF_F2L);
    float* f12 = (float*)(w + OFF_F12);
    float* f22 = (float*)(w + OFF_F22);
    float* FM1 = (float*)(w + OFF_FM1);
    float* FM2 = (float*)(w + OFF_FM2);
    uint64_t* adjb = (uint64_t*)(w + OFF_ADJ);
    float* Pa2 = (float*)(w + OFF_PA2);

    prep_xb_k<<<8192, 256, 0, stream>>>(x, xb);
    prep_WT_k<<<1024, 256, 0, stream>>>(Ws, WT);
    prep_WoT_k<<<96, 256, 0, stream>>>(W_out, WoT);
    prep_adj_k<<<1024, 256, 0, stream>>>(adj, adjb);

    gemm1_k<<<dim3(64, 8), 256, 0, stream>>>(xb, WT, a_s, H1b, f1L, f2L);
    repack1_k<<<dim3(128, 8), 256, 0, stream>>>(H1b, Bp1);
    fmax_k<<<8, 256, 0, stream>>>(f2L, FM1, NN);
    attn1_k<<<dim3(32, 8), 512, 0, stream>>>(Bp1, adjb, f1L, f2L, FM1, x2b);

    gemm2_k<<<64, 256, 0, stream>>>(x2b, WoT, a_out, H2b, f12, f22);
    repack2_k<<<128, 256, 0, stream>>>(H2b, Bp2);
    fmax_k<<<1, 256, 0, stream>>>(f22, FM2, NN);
    attn2_k<<<dim3(32, 16), 512, 0, stream>>>(Bp2, adjb, f12, f22, FM2, Pa2);
    attn2fin_k<<<1024, 256, 0, stream>>>(Pa2, out);
}

// Round 3
// 265.498 us; speedup vs baseline: 1.5431x; 1.1947x over previous
//
#include <hip/hip_runtime.h>
#include <hip/hip_bf16.h>
#include <stdint.h>

#define NN 4096      // nodes
#define NF 512       // NFEAT = NHEADS*NHID
#define NH 64        // NHID
#define NCLS 40      // NCLASS
#define NHEADS 8
#define H2C 48       // padded class width (3 MFMA n-chunks)
#define LOG2E 1.4426950408889634f

typedef __attribute__((ext_vector_type(8))) short bh8;
typedef __attribute__((ext_vector_type(4))) float f32x4;

__device__ __forceinline__ unsigned short f2bu(float f) {
    union { float f; unsigned u; } v; v.f = f;
    unsigned r = (v.u + 0x7FFFu + ((v.u >> 16) & 1u)) >> 16;
    return (unsigned short)r;
}
__device__ __forceinline__ float lrelu(float x) { return fmaxf(x, 0.2f * x); }
__device__ __forceinline__ float elu1(float x) { return x > 0.f ? x : expm1f(x); }

// p = exp2(max(f2e + c1, 0.2*f2e + c2)), masked; c1 = f1-mL, c2 = 0.2*f1-mL (log2 domain)
__device__ __forceinline__ float scoree(float f2e, float c1, float c2, unsigned ab, int e) {
    float s = fmaxf(f2e + c1, __builtin_fmaf(0.2f, f2e, c2));
    float p;
    asm("v_exp_f32 %0, %1" : "=v"(p) : "v"(s));
    return (ab & (1u << e)) ? p : 0.0f;
}

// ---------------- prep kernels ----------------
__global__ void prep_xb_k(const float* __restrict__ x, unsigned short* __restrict__ xb) {
    int idx = blockIdx.x * 256 + threadIdx.x;
    xb[idx] = f2bu(x[idx]);
}
__global__ void prep_WT_k(const float* __restrict__ Ws, unsigned short* __restrict__ WT) {
    int idx = blockIdx.x * 256 + threadIdx.x;           // c*512 + k
    int c = idx >> 9, k = idx & 511;
    WT[idx] = f2bu(Ws[(size_t)(c >> 6) * (NF * NH) + (size_t)k * NH + (c & 63)]);
}
__global__ void prep_WoT_k(const float* __restrict__ Wo, unsigned short* __restrict__ WoT) {
    int idx = blockIdx.x * 256 + threadIdx.x;           // c*512 + k, 48*512
    int c = idx >> 9, k = idx & 511;
    WoT[idx] = f2bu(c < NCLS ? Wo[(size_t)k * NCLS + c] : 0.f);
}
// adjacency -> byte-planes: adjp[(i*4+grp)*128 + jt] bit e = adj[i][jt*32+grp*8+e]
__global__ __launch_bounds__(256) void prep_adj_k(const float* __restrict__ adj,
                                                  unsigned char* __restrict__ adjp) {
    int w = threadIdx.x >> 6, lane = threadIdx.x & 63;
    int i = blockIdx.x * 4 + w;
    const float* row = adj + (size_t)i * NN;
    for (int t = 0; t < 64; ++t) {
        uint64_t m = __ballot(row[t * 64 + lane] > 0.f);
        if (lane < 8) {
            unsigned char mb = (unsigned char)(m >> (8 * lane));
            int grp = lane & 3, jt = 2 * t + (lane >> 2);
            adjp[((size_t)i * 4 + grp) * 128 + jt] = mb;
        }
    }
}

// ---------------- GEMM1: H1 = x @ Wcat  + f1/f2 epilogue ----------------
__global__ __launch_bounds__(256) void gemm1_k(const unsigned short* __restrict__ xb,
                                               const unsigned short* __restrict__ WT,
                                               const float* __restrict__ a_s,
                                               unsigned short* __restrict__ H1b,
                                               float* __restrict__ f1L,
                                               float* __restrict__ f2L) {
    __shared__ unsigned short xs[64 * 40];
    __shared__ unsigned short wsm[64 * 40];
    const int tid = threadIdx.x;
    const int w = tid >> 6, lane = tid & 63, r16 = lane & 15, grp = lane >> 4;
    const int i0 = blockIdx.x << 6, h = blockIdx.y, c0 = h << 6;
    const int srow = tid >> 2, sseg = tid & 3;
    const unsigned short* xsrc = xb + (size_t)(i0 + srow) * NF + sseg * 8;
    const unsigned short* wsrc = WT + (size_t)(c0 + srow) * NF + sseg * 8;
    f32x4 a0 = {0,0,0,0}, a1 = {0,0,0,0}, a2 = {0,0,0,0}, a3 = {0,0,0,0};
    for (int kb = 0; kb < NF; kb += 32) {
        *(bh8*)(xs + srow * 40 + sseg * 8) = *(const bh8*)(xsrc + kb);
        *(bh8*)(wsm + srow * 40 + sseg * 8) = *(const bh8*)(wsrc + kb);
        __syncthreads();
        bh8 af = *(const bh8*)(xs + (w * 16 + r16) * 40 + grp * 8);
        bh8 b0 = *(const bh8*)(wsm + (r16) * 40 + grp * 8);
        bh8 b1 = *(const bh8*)(wsm + (16 + r16) * 40 + grp * 8);
        bh8 b2 = *(const bh8*)(wsm + (32 + r16) * 40 + grp * 8);
        bh8 b3 = *(const bh8*)(wsm + (48 + r16) * 40 + grp * 8);
        a0 = __builtin_amdgcn_mfma_f32_16x16x32_bf16(af, b0, a0, 0, 0, 0);
        a1 = __builtin_amdgcn_mfma_f32_16x16x32_bf16(af, b1, a1, 0, 0, 0);
        a2 = __builtin_amdgcn_mfma_f32_16x16x32_bf16(af, b2, a2, 0, 0, 0);
        a3 = __builtin_amdgcn_mfma_f32_16x16x32_bf16(af, b3, a3, 0, 0, 0);
        __syncthreads();
    }
    const float* ap = a_s + h * 128;
    float a1v[4], a2v[4];
#pragma unroll
    for (int n = 0; n < 4; ++n) { a1v[n] = ap[r16 + 16 * n]; a2v[n] = ap[64 + r16 + 16 * n]; }
#pragma unroll
    for (int r = 0; r < 4; ++r) {
        const int orow = i0 + w * 16 + grp * 4 + r;
        unsigned short* o = H1b + (size_t)orow * NF + c0 + r16;
        o[0] = f2bu(a0[r]);  o[16] = f2bu(a1[r]);  o[32] = f2bu(a2[r]);  o[48] = f2bu(a3[r]);
        float s1 = a0[r] * a1v[0] + a1[r] * a1v[1] + a2[r] * a1v[2] + a3[r] * a1v[3];
        float s2 = a0[r] * a2v[0] + a1[r] * a2v[1] + a2[r] * a2v[2] + a3[r] * a2v[3];
#pragma unroll
        for (int o2 = 1; o2 < 16; o2 <<= 1) { s1 += __shfl_xor(s1, o2); s2 += __shfl_xor(s2, o2); }
        if (r16 == 0) { f1L[h * NN + orow] = s1 * LOG2E; f2L[h * NN + orow] = s2 * LOG2E; }
    }
}

// ---------------- GEMM2: H2 = x2 @ W_out + f epilogue ----------------
__global__ __launch_bounds__(256) void gemm2_k(const unsigned short* __restrict__ x2b,
                                               const unsigned short* __restrict__ WoT,
                                               const float* __restrict__ a_out,
                                               unsigned short* __restrict__ H2b,
                                               float* __restrict__ f12L,
                                               float* __restrict__ f22L) {
    __shared__ unsigned short xs[64 * 40];
    __shared__ unsigned short wsm[48 * 40];
    const int tid = threadIdx.x;
    const int w = tid >> 6, lane = tid & 63, r16 = lane & 15, grp = lane >> 4;
    const int i0 = blockIdx.x << 6;
    const int srow = tid >> 2, sseg = tid & 3;
    const unsigned short* xsrc = x2b + (size_t)(i0 + srow) * NF + sseg * 8;
    const unsigned short* wsrc = WoT + (size_t)srow * NF + sseg * 8;
    f32x4 a0 = {0,0,0,0}, a1 = {0,0,0,0}, a2 = {0,0,0,0};
    for (int kb = 0; kb < NF; kb += 32) {
        *(bh8*)(xs + srow * 40 + sseg * 8) = *(const bh8*)(xsrc + kb);
        if (tid < 192) *(bh8*)(wsm + srow * 40 + sseg * 8) = *(const bh8*)(wsrc + kb);
        __syncthreads();
        bh8 af = *(const bh8*)(xs + (w * 16 + r16) * 40 + grp * 8);
        bh8 b0 = *(const bh8*)(wsm + (r16) * 40 + grp * 8);
        bh8 b1 = *(const bh8*)(wsm + (16 + r16) * 40 + grp * 8);
        bh8 b2 = *(const bh8*)(wsm + (32 + r16) * 40 + grp * 8);
        a0 = __builtin_amdgcn_mfma_f32_16x16x32_bf16(af, b0, a0, 0, 0, 0);
        a1 = __builtin_amdgcn_mfma_f32_16x16x32_bf16(af, b1, a1, 0, 0, 0);
        a2 = __builtin_amdgcn_mfma_f32_16x16x32_bf16(af, b2, a2, 0, 0, 0);
        __syncthreads();
    }
    float a1v[3], a2v[3];
#pragma unroll
    for (int n = 0; n < 3; ++n) {
        int col = r16 + 16 * n;
        a1v[n] = col < NCLS ? a_out[col] : 0.f;
        a2v[n] = col < NCLS ? a_out[NCLS + col] : 0.f;
    }
#pragma unroll
    for (int r = 0; r < 4; ++r) {
        const int orow = i0 + w * 16 + grp * 4 + r;
        unsigned short* o = H2b + (size_t)orow * H2C + r16;
        o[0] = f2bu(a0[r]);  o[16] = f2bu(a1[r]);  o[32] = f2bu(a2[r]);
        float s1 = a0[r] * a1v[0] + a1[r] * a1v[1] + a2[r] * a1v[2];
        float s2 = a0[r] * a2v[0] + a1[r] * a2v[1] + a2[r] * a2v[2];
#pragma unroll
        for (int o2 = 1; o2 < 16; o2 <<= 1) { s1 += __shfl_xor(s1, o2); s2 += __shfl_xor(s2, o2); }
        if (r16 == 0) { f12L[orow] = s1 * LOG2E; f22L[orow] = s2 * LOG2E; }
    }
}

// ---------------- repack H1b -> B-panels Bp1[h][jt][f][lane][e] ----------------
__global__ __launch_bounds__(256) void repack1_k(const unsigned short* __restrict__ H1b,
                                                 unsigned short* __restrict__ Bp1) {
    __shared__ unsigned short t2[32][72];
    const int jt = blockIdx.x, h = blockIdx.y, tid = threadIdx.x;
    const int tr = tid >> 3, tc = tid & 7;
    *(bh8*)(&t2[tr][tc * 8]) = *(const bh8*)(H1b + (size_t)(jt * 32 + tr) * NF + h * 64 + tc * 8);
    __syncthreads();
    const int f = tid >> 6, l = tid & 63;
    unsigned short tmp[8];
#pragma unroll
    for (int e = 0; e < 8; ++e) tmp[e] = t2[(l >> 4) * 8 + e][f * 16 + (l & 15)];
    *(bh8*)(Bp1 + ((size_t)(h * 128 + jt) * 2048) + f * 512 + l * 8) = *(bh8*)tmp;
}

// ---------------- repack H2b -> Bp2[jt][f<3][lane][e] ----------------
__global__ __launch_bounds__(256) void repack2_k(const unsigned short* __restrict__ H2b,
                                                 unsigned short* __restrict__ Bp2) {
    __shared__ unsigned short t2[32][56];
    const int jt = blockIdx.x, tid = threadIdx.x;
    const int tr = tid >> 3, tc = tid & 7;
    if (tc < 6)
        *(bh8*)(&t2[tr][tc * 8]) = *(const bh8*)(H2b + (size_t)(jt * 32 + tr) * H2C + tc * 8);
    __syncthreads();
    const int f = tid >> 6, l = tid & 63;
    if (f < 3) {
        unsigned short tmp[8];
#pragma unroll
        for (int e = 0; e < 8; ++e) tmp[e] = t2[(l >> 4) * 8 + e][f * 16 + (l & 15)];
        *(bh8*)(Bp2 + (size_t)jt * 1536 + f * 512 + l * 8) = *(bh8*)tmp;
    }
}

// ---------------- max over rows ----------------
__global__ void fmax_k(const float* __restrict__ v, float* __restrict__ out, int n) {
    __shared__ float red[256];
    int t = threadIdx.x;
    const float* p = v + (size_t)blockIdx.x * n;
    float mx = -1e30f;
    for (int j = t; j < n; j += 256) mx = fmaxf(mx, p[j]);
    red[t] = mx; __syncthreads();
    for (int s = 128; s > 0; s >>= 1) { if (t < s) red[t] = fmaxf(red[t], red[t + s]); __syncthreads(); }
    if (t == 0) out[blockIdx.x] = red[0];
}

// ---------------- attn layer 1: barrier-free, direct L2 panel reads ----------------
__global__ __launch_bounds__(256) void attn1_k(const unsigned short* __restrict__ Bp1,
                                               const unsigned char* __restrict__ adjp,
                                               const float* __restrict__ f1L,
                                               const float* __restrict__ f2L,
                                               const float* __restrict__ FM1,
                                               unsigned short* __restrict__ x2b) {
    const int tid = threadIdx.x, w = tid >> 6, lane = tid & 63;
    const int r16 = lane & 15, grp = lane >> 4;
    const int h = blockIdx.y;
    const int i0 = blockIdx.x * 64 + w * 16;
    const int i = i0 + r16;
    const float f1v = f1L[h * NN + i];
    const float mL = lrelu(f1v + FM1[h]);
    const float c1 = f1v - mL;
    const float c2 = __builtin_fmaf(0.2f, f1v, -mL);
    const float* f2p = f2L + h * NN;
    const unsigned char* adjr = adjp + ((size_t)i * 4 + grp) * 128;
    const unsigned short* Bbase = Bp1 + (size_t)h * 128 * 2048 + lane * 8;
    f32x4 acc0 = {0,0,0,0}, acc1 = {0,0,0,0}, acc2 = {0,0,0,0}, acc3 = {0,0,0,0}, accd = {0,0,0,0};
    const short ov = (r16 == 0) ? (short)0x3F80 : (short)0;
    bh8 ones;
#pragma unroll
    for (int e = 0; e < 8; ++e) ones[e] = ov;
    bh8 nb0, nb1, nb2, nb3;
    float4 nfa, nfb;
#define PREF1(JT) { const unsigned short* Bn = Bbase + (size_t)(JT) * 2048;              \
        nb0 = *(const bh8*)(Bn);        nb1 = *(const bh8*)(Bn + 512);                    \
        nb2 = *(const bh8*)(Bn + 1024); nb3 = *(const bh8*)(Bn + 1536);                   \
        nfa = *(const float4*)(f2p + (JT) * 32 + grp * 8);                                \
        nfb = *(const float4*)(f2p + (JT) * 32 + grp * 8 + 4); }
    PREF1(0);
    for (int jt4 = 0; jt4 < 32; ++jt4) {
        const unsigned mdw = *(const unsigned*)(adjr + jt4 * 4);
#pragma unroll
        for (int u = 0; u < 4; ++u) {
            const int jt = jt4 * 4 + u;
            bh8 b0 = nb0, b1 = nb1, b2 = nb2, b3 = nb3;
            float4 fa = nfa, fb = nfb;
            if (jt < 127) PREF1(jt + 1);
            const unsigned ab = (mdw >> (u * 8)) & 0xFFu;
            float fe[8] = {fa.x, fa.y, fa.z, fa.w, fb.x, fb.y, fb.z, fb.w};
            union { bh8 v; unsigned u32[4]; } pk;
#pragma unroll
            for (int e2 = 0; e2 < 4; ++e2) {
                float p0 = scoree(fe[2 * e2], c1, c2, ab, 2 * e2);
                float p1 = scoree(fe[2 * e2 + 1], c1, c2, ab, 2 * e2 + 1);
                pk.u32[e2] = __builtin_amdgcn_perm(__builtin_bit_cast(unsigned, p1),
                                                   __builtin_bit_cast(unsigned, p0), 0x07060302u);
            }
            acc0 = __builtin_amdgcn_mfma_f32_16x16x32_bf16(pk.v, b0, acc0, 0, 0, 0);
            acc1 = __builtin_amdgcn_mfma_f32_16x16x32_bf16(pk.v, b1, acc1, 0, 0, 0);
            acc2 = __builtin_amdgcn_mfma_f32_16x16x32_bf16(pk.v, b2, acc2, 0, 0, 0);
            acc3 = __builtin_amdgcn_mfma_f32_16x16x32_bf16(pk.v, b3, acc3, 0, 0, 0);
            accd = __builtin_amdgcn_mfma_f32_16x16x32_bf16(pk.v, ones, accd, 0, 0, 0);
        }
    }
#undef PREF1
#pragma unroll
    for (int r = 0; r < 4; ++r) {
        const float den = __shfl(accd[r], lane & 48);
        const float inv = 1.0f / den;
        unsigned short* o = x2b + (size_t)(i0 + grp * 4 + r) * NF + h * 64 + r16;
        o[0]  = f2bu(elu1(acc0[r] * inv));
        o[16] = f2bu(elu1(acc1[r] * inv));
        o[32] = f2bu(elu1(acc2[r] * inv));
        o[48] = f2bu(elu1(acc3[r] * inv));
    }
}

// ---------------- attn layer 2 partial: grid (64 i-blocks, 16 j-chunks) ----------------
__global__ __launch_bounds__(256) void attn2_k(const unsigned short* __restrict__ Bp2,
                                               const unsigned char* __restrict__ adjp,
                                               const float* __restrict__ f12L,
                                               const float* __restrict__ f22L,
                                               const float* __restrict__ FM2,
                                               float* __restrict__ Pa2) {
    const int tid = threadIdx.x, w = tid >> 6, lane = tid & 63;
    const int r16 = lane & 15, grp = lane >> 4;
    const int ch = blockIdx.y;
    const int i0 = blockIdx.x * 64 + w * 16;
    const int i = i0 + r16;
    const float f1v = f12L[i];
    const float mL = lrelu(f1v + FM2[0]);
    const float c1 = f1v - mL;
    const float c2 = __builtin_fmaf(0.2f, f1v, -mL);
    const unsigned char* adjr = adjp + ((size_t)i * 4 + grp) * 128;
    f32x4 acc0 = {0,0,0,0}, acc1 = {0,0,0,0}, acc2 = {0,0,0,0}, accd = {0,0,0,0};
    const short ov = (r16 == 0) ? (short)0x3F80 : (short)0;
    bh8 ones;
#pragma unroll
    for (int e = 0; e < 8; ++e) ones[e] = ov;
    const int jt0 = ch * 8;
    const unsigned short* Bbase = Bp2 + lane * 8;
    bh8 nb0, nb1, nb2;
    float4 nfa, nfb;
#define PREF2(JT) { const unsigned short* Bn = Bbase + (size_t)(JT) * 1536;              \
        nb0 = *(const bh8*)(Bn); nb1 = *(const bh8*)(Bn + 512); nb2 = *(const bh8*)(Bn + 1024); \
        nfa = *(const float4*)(f22L + (JT) * 32 + grp * 8);                               \
        nfb = *(const float4*)(f22L + (JT) * 32 + grp * 8 + 4); }
    PREF2(jt0);
    for (int jt4 = 0; jt4 < 2; ++jt4) {
        const unsigned mdw = *(const unsigned*)(adjr + jt0 + jt4 * 4);
#pragma unroll
        for (int u = 0; u < 4; ++u) {
            const int jt = jt0 + jt4 * 4 + u;
            bh8 b0 = nb0, b1 = nb1, b2 = nb2;
            float4 fa = nfa, fb = nfb;
            if (jt4 * 4 + u < 7) PREF2(jt + 1);
            const unsigned ab = (mdw >> (u * 8)) & 0xFFu;
            float fe[8] = {fa.x, fa.y, fa.z, fa.w, fb.x, fb.y, fb.z, fb.w};
            union { bh8 v; unsigned u32[4]; } pk;
#pragma unroll
            for (int e2 = 0; e2 < 4; ++e2) {
                float p0 = scoree(fe[2 * e2], c1, c2, ab, 2 * e2);
                float p1 = scoree(fe[2 * e2 + 1], c1, c2, ab, 2 * e2 + 1);
                pk.u32[e2] = __builtin_amdgcn_perm(__builtin_bit_cast(unsigned, p1),
                                                   __builtin_bit_cast(unsigned, p0), 0x07060302u);
            }
            acc0 = __builtin_amdgcn_mfma_f32_16x16x32_bf16(pk.v, b0, acc0, 0, 0, 0);
            acc1 = __builtin_amdgcn_mfma_f32_16x16x32_bf16(pk.v, b1, acc1, 0, 0, 0);
            acc2 = __builtin_amdgcn_mfma_f32_16x16x32_bf16(pk.v, b2, acc2, 0, 0, 0);
            accd = __builtin_amdgcn_mfma_f32_16x16x32_bf16(pk.v, ones, accd, 0, 0, 0);
        }
    }
#undef PREF2
#pragma unroll
    for (int r = 0; r < 4; ++r) {
        const int row = i0 + grp * 4 + r;
        float* prow = Pa2 + ((size_t)ch * NN + row) * 52;
        prow[r16] = acc0[r];
        prow[16 + r16] = acc1[r];
        prow[32 + r16] = acc2[r];
        if (r16 == 0) prow[48] = accd[r];
    }
}

// ---------------- attn2 finish: reduce chunks, elu, log_softmax ----------------
__global__ __launch_bounds__(256) void attn2fin_k(const float* __restrict__ Pa2,
                                                  float* __restrict__ out) {
    const int tid = threadIdx.x;
    const int row = blockIdx.x * 4 + (tid >> 6);
    const int lane = tid & 63;
    float s = 0.f;
    if (lane < 49) {
#pragma unroll
        for (int c = 0; c < 16; ++c) s += Pa2[((size_t)c * NN + row) * 52 + lane];
    }
    const float den = __shfl(s, 48);
    const float inv = 1.0f / den;
    float v = (lane < NCLS) ? elu1(s * inv) : -3.0e38f;
    float mx = v;
#pragma unroll
    for (int o = 1; o < 64; o <<= 1) mx = fmaxf(mx, __shfl_xor(mx, o));
    float ex = (lane < NCLS) ? __expf(v - mx) : 0.f;
#pragma unroll
    for (int o = 1; o < 64; o <<= 1) ex += __shfl_xor(ex, o);
    const float lse = mx + logf(ex);
    if (lane < NCLS) out[(size_t)row * NCLS + lane] = v - lse;
}

// ---------------- workspace layout (bytes) ----------------
#define OFF_XB   0ULL           // 4096*512*2 = 4194304
#define OFF_WT   4194304ULL     // 512*512*2  = 524288
#define OFF_WOT  4718592ULL     // 48*512*2   = 49152
#define OFF_H1B  4767744ULL     // 4096*512*2 = 4194304
#define OFF_BP1  8962048ULL     // 8*128*2048*2 = 4194304
#define OFF_X2B  13156352ULL    // 4096*512*2 = 4194304
#define OFF_H2B  17350656ULL    // 4096*48*2 = 393216
#define OFF_BP2  17743872ULL    // 128*1536*2 = 393216
#define OFF_F1L  18137088ULL    // 8*4096*4 = 131072
#define OFF_F2L  18268160ULL    // 131072
#define OFF_F12  18399232ULL    // 16384
#define OFF_F22  18415616ULL    // 16384
#define OFF_FM1  18432000ULL    // 256
#define OFF_FM2  18432256ULL    // 256
#define OFF_ADJ  18432512ULL    // 4096*4*128 = 2097152
#define OFF_PA2  20529664ULL    // 16*4096*52*4 = 13631488  -> end 34161152

extern "C" void kernel_launch(void* const* d_in, const int* in_sizes, int n_in,
                              void* d_out, int out_size, void* d_ws, size_t ws_size,
                              hipStream_t stream) {
    const float* x     = (const float*)d_in[0];
    const float* adj   = (const float*)d_in[1];
    const float* Ws    = (const float*)d_in[2];
    const float* a_s   = (const float*)d_in[3];
    const float* W_out = (const float*)d_in[4];
    const float* a_out = (const float*)d_in[5];
    float* out = (float*)d_out;
    char* w = (char*)d_ws;

    unsigned short* xb  = (unsigned short*)(w + OFF_XB);
    unsigned short* WT  = (unsigned short*)(w + OFF_WT);
    unsigned short* WoT = (unsigned short*)(w + OFF_WOT);
    unsigned short* H1b = (unsigned short*)(w + OFF_H1B);
    unsigned short* Bp1 = (unsigned short*)(w + OFF_BP1);
    unsigned short* x2b = (unsigned short*)(w + OFF_X2B);
    unsigned short* H2b = (unsigned short*)(w + OFF_H2B);
    unsigned short* Bp2 = (unsigned short*)(w + OFF_BP2);
    float* f1L = (float*)(w + OFF_F1L);
    float* f2L = (float*)(w + OFF_F2L);
    float* f12 = (float*)(w + OFF_F12);
    float* f22 = (float*)(w + OFF_F22);
    float* FM1 = (float*)(w + OFF_FM1);
    float* FM2 = (float*)(w + OFF_FM2);
    unsigned char* adjp = (unsigned char*)(w + OFF_ADJ);
    float* Pa2 = (float*)(w + OFF_PA2);

    prep_xb_k<<<8192, 256, 0, stream>>>(x, xb);
    prep_WT_k<<<1024, 256, 0, stream>>>(Ws, WT);
    prep_WoT_k<<<96, 256, 0, stream>>>(W_out, WoT);
    prep_adj_k<<<1024, 256, 0, stream>>>(adj, adjp);

    gemm1_k<<<dim3(64, 8), 256, 0, stream>>>(xb, WT, a_s, H1b, f1L, f2L);
    repack1_k<<<dim3(128, 8), 256, 0, stream>>>(H1b, Bp1);
    fmax_k<<<8, 256, 0, stream>>>(f2L, FM1, NN);
    attn1_k<<<dim3(64, 8), 256, 0, stream>>>(Bp1, adjp, f1L, f2L, FM1, x2b);

    gemm2_k<<<64, 256, 0, stream>>>(x2b, WoT, a_out, H2b, f12, f22);
    repack2_k<<<128, 256, 0, stream>>>(H2b, Bp2);
    fmax_k<<<1, 256, 0, stream>>>(f22, FM2, NN);
    attn2_k<<<dim3(64, 16), 256, 0, stream>>>(Bp2, adjp, f12, f22, FM2, Pa2);
    attn2fin_k<<<1024, 256, 0, stream>>>(Pa2, out);
}

// Round 4
// 260.660 us; speedup vs baseline: 1.5718x; 1.0186x over previous
//
#include <hip/hip_runtime.h>
#include <hip/hip_bf16.h>
#include <stdint.h>

#define NN 4096      // nodes
#define NF 512       // NFEAT = NHEADS*NHID
#define NH 64        // NHID
#define NCLS 40      // NCLASS
#define NHEADS 8
#define LOG2E 1.4426950408889634f

typedef __attribute__((ext_vector_type(8))) short bh8;
typedef __attribute__((ext_vector_type(4))) float f32x4;

__device__ __forceinline__ unsigned short f2bu(float f) {
    union { float f; unsigned u; } v; v.f = f;
    unsigned r = (v.u + 0x7FFFu + ((v.u >> 16) & 1u)) >> 16;
    return (unsigned short)r;
}
__device__ __forceinline__ float lrelu(float x) { return fmaxf(x, 0.2f * x); }
__device__ __forceinline__ float elu1(float x) { return x > 0.f ? x : expm1f(x); }

// ordered-uint encode/decode for float atomicMax
__device__ __forceinline__ unsigned fenc(float f) {
    unsigned u = __builtin_bit_cast(unsigned, f);
    return ((int)u < 0) ? ~u : (u | 0x80000000u);
}
__device__ __forceinline__ float fdec(unsigned k) {
    unsigned u = (k & 0x80000000u) ? (k ^ 0x80000000u) : ~k;
    return __builtin_bit_cast(float, u);
}

// unmasked score: p = exp2(max(f2e + c1, 0.2*f2e + c2))
__device__ __forceinline__ float scoref(float f2e, float c1, float c2) {
    float s = fmaxf(f2e + c1, __builtin_fmaf(0.2f, f2e, c2));
    float p;
    asm("v_exp_f32 %0, %1" : "=v"(p) : "v"(s));
    return p;
}
// mask p with bit `bit` of mdw: sign-replicate + AND on float bits (2 VALU)
__device__ __forceinline__ float maskp(float p, unsigned mdw, int bit) {
    int m = (int)(mdw << (31 - bit)) >> 31;
    return __builtin_bit_cast(float, __builtin_bit_cast(unsigned, p) & (unsigned)m);
}
// pack two f32 -> bf16 pair (RN)
__device__ __forceinline__ unsigned pack2(float x, float y) {
    unsigned ux = __builtin_bit_cast(unsigned, x), uy = __builtin_bit_cast(unsigned, y);
    ux += 0x7FFFu + ((ux >> 16) & 1u);
    uy += 0x7FFFu + ((uy >> 16) & 1u);
    return __builtin_amdgcn_perm(uy, ux, 0x07060302u);
}

// ---------------- prep kernels ----------------
__global__ void prep_xb_k(const float* __restrict__ x, unsigned short* __restrict__ xb) {
    int idx = blockIdx.x * 256 + threadIdx.x;
    xb[idx] = f2bu(x[idx]);
}
// merged weight converts: WT (512x512) then WoT (48x512)
__global__ void prep_W_k(const float* __restrict__ Ws, const float* __restrict__ Wo,
                         unsigned short* __restrict__ WT, unsigned short* __restrict__ WoT) {
    int idx = blockIdx.x * 256 + threadIdx.x;
    if (idx < 262144) {
        int c = idx >> 9, k = idx & 511;
        WT[idx] = f2bu(Ws[(size_t)(c >> 6) * (NF * NH) + (size_t)k * NH + (c & 63)]);
    } else {
        int j = idx - 262144;
        int c = j >> 9, k = j & 511;
        WoT[j] = f2bu(c < NCLS ? Wo[(size_t)k * NCLS + c] : 0.f);
    }
}
// adjacency -> byte planes + FM init
__global__ __launch_bounds__(256) void prep_adj_k(const float* __restrict__ adj,
                                                  unsigned char* __restrict__ adjp,
                                                  unsigned* __restrict__ FM1u,
                                                  unsigned* __restrict__ FM2u) {
    if (blockIdx.x == 0) {
        if (threadIdx.x < 8) FM1u[threadIdx.x] = 0u;
        if (threadIdx.x == 8) FM2u[0] = 0u;
    }
    int w = threadIdx.x >> 6, lane = threadIdx.x & 63;
    int i = blockIdx.x * 4 + w;
    const float* row = adj + (size_t)i * NN;
    for (int t = 0; t < 64; ++t) {
        uint64_t m = __ballot(row[t * 64 + lane] > 0.f);
        if (lane < 8) {
            unsigned char mb = (unsigned char)(m >> (8 * lane));
            int grp = lane & 3, jt = 2 * t + (lane >> 2);
            adjp[((size_t)i * 4 + grp) * 128 + jt] = mb;
        }
    }
}

// ---------------- GEMM1: Bp1 = pack(x @ Wcat), f1/f2 + FM1 epilogue ----------------
__global__ __launch_bounds__(256) void gemm1_k(const unsigned short* __restrict__ xb,
                                               const unsigned short* __restrict__ WT,
                                               const float* __restrict__ a_s,
                                               unsigned short* __restrict__ Bp1,
                                               float* __restrict__ f1L,
                                               float* __restrict__ f2L,
                                               unsigned* __restrict__ FM1u) {
    __shared__ unsigned short xs[64 * 40];
    __shared__ unsigned short wsm[64 * 40];
    const int tid = threadIdx.x;
    const int w = tid >> 6, lane = tid & 63, r16 = lane & 15, grp = lane >> 4;
    const int i0 = blockIdx.x << 6, h = blockIdx.y, c0 = h << 6;
    const int srow = tid >> 2, sseg = tid & 3;
    const unsigned short* xsrc = xb + (size_t)(i0 + srow) * NF + sseg * 8;
    const unsigned short* wsrc = WT + (size_t)(c0 + srow) * NF + sseg * 8;
    f32x4 a0 = {0,0,0,0}, a1 = {0,0,0,0}, a2 = {0,0,0,0}, a3 = {0,0,0,0};
    for (int kb = 0; kb < NF; kb += 32) {
        *(bh8*)(xs + srow * 40 + sseg * 8) = *(const bh8*)(xsrc + kb);
        *(bh8*)(wsm + srow * 40 + sseg * 8) = *(const bh8*)(wsrc + kb);
        __syncthreads();
        bh8 af = *(const bh8*)(xs + (w * 16 + r16) * 40 + grp * 8);
        bh8 b0 = *(const bh8*)(wsm + (r16) * 40 + grp * 8);
        bh8 b1 = *(const bh8*)(wsm + (16 + r16) * 40 + grp * 8);
        bh8 b2 = *(const bh8*)(wsm + (32 + r16) * 40 + grp * 8);
        bh8 b3 = *(const bh8*)(wsm + (48 + r16) * 40 + grp * 8);
        a0 = __builtin_amdgcn_mfma_f32_16x16x32_bf16(af, b0, a0, 0, 0, 0);
        a1 = __builtin_amdgcn_mfma_f32_16x16x32_bf16(af, b1, a1, 0, 0, 0);
        a2 = __builtin_amdgcn_mfma_f32_16x16x32_bf16(af, b2, a2, 0, 0, 0);
        a3 = __builtin_amdgcn_mfma_f32_16x16x32_bf16(af, b3, a3, 0, 0, 0);
        __syncthreads();
    }
    // ---- direct B-panel write: Bp1[h][jt][n][lane'][e] ----
    const int jt = (i0 >> 5) + (w >> 1);
    const int kg = ((w & 1) << 1) + (grp >> 1);
    const int lanep = kg * 16 + r16;
    const int ebase = (grp & 1) * 4;
    unsigned short* bp = Bp1 + ((size_t)(h * 128 + jt)) * 2048 + lanep * 8 + ebase;
    {
        uint2 v;
        v.x = pack2(a0[0], a0[1]); v.y = pack2(a0[2], a0[3]); *(uint2*)(bp + 0 * 512) = v;
        v.x = pack2(a1[0], a1[1]); v.y = pack2(a1[2], a1[3]); *(uint2*)(bp + 1 * 512) = v;
        v.x = pack2(a2[0], a2[1]); v.y = pack2(a2[2], a2[3]); *(uint2*)(bp + 2 * 512) = v;
        v.x = pack2(a3[0], a3[1]); v.y = pack2(a3[2], a3[3]); *(uint2*)(bp + 3 * 512) = v;
    }
    // ---- f1/f2 epilogue + FM1 ----
    const float* ap = a_s + h * 128;
    float a1v[4], a2v[4];
#pragma unroll
    for (int n = 0; n < 4; ++n) { a1v[n] = ap[r16 + 16 * n]; a2v[n] = ap[64 + r16 + 16 * n]; }
    float wmax = -3.0e38f;
#pragma unroll
    for (int r = 0; r < 4; ++r) {
        const int orow = i0 + w * 16 + grp * 4 + r;
        float s1 = a0[r] * a1v[0] + a1[r] * a1v[1] + a2[r] * a1v[2] + a3[r] * a1v[3];
        float s2 = a0[r] * a2v[0] + a1[r] * a2v[1] + a2[r] * a2v[2] + a3[r] * a2v[3];
#pragma unroll
        for (int o2 = 1; o2 < 16; o2 <<= 1) { s1 += __shfl_xor(s1, o2); s2 += __shfl_xor(s2, o2); }
        s1 *= LOG2E; s2 *= LOG2E;
        if (r16 == 0) { f1L[h * NN + orow] = s1; f2L[h * NN + orow] = s2; }
        wmax = fmaxf(wmax, s2);
    }
    wmax = fmaxf(wmax, __shfl_xor(wmax, 16));
    wmax = fmaxf(wmax, __shfl_xor(wmax, 32));
    if (lane == 0) atomicMax(&FM1u[h], fenc(wmax));
}

// ---------------- GEMM2: Bp2 = pack(x2 @ W_out), f12/f22 + FM2 epilogue ----------------
__global__ __launch_bounds__(256) void gemm2_k(const unsigned short* __restrict__ x2b,
                                               const unsigned short* __restrict__ WoT,
                                               const float* __restrict__ a_out,
                                               unsigned short* __restrict__ Bp2,
                                               float* __restrict__ f12L,
                                               float* __restrict__ f22L,
                                               unsigned* __restrict__ FM2u) {
    __shared__ unsigned short xs[64 * 40];
    __shared__ unsigned short wsm[48 * 40];
    const int tid = threadIdx.x;
    const int w = tid >> 6, lane = tid & 63, r16 = lane & 15, grp = lane >> 4;
    const int i0 = blockIdx.x << 6;
    const int srow = tid >> 2, sseg = tid & 3;
    const unsigned short* xsrc = x2b + (size_t)(i0 + srow) * NF + sseg * 8;
    const unsigned short* wsrc = WoT + (size_t)srow * NF + sseg * 8;
    f32x4 a0 = {0,0,0,0}, a1 = {0,0,0,0}, a2 = {0,0,0,0};
    for (int kb = 0; kb < NF; kb += 32) {
        *(bh8*)(xs + srow * 40 + sseg * 8) = *(const bh8*)(xsrc + kb);
        if (tid < 192) *(bh8*)(wsm + srow * 40 + sseg * 8) = *(const bh8*)(wsrc + kb);
        __syncthreads();
        bh8 af = *(const bh8*)(xs + (w * 16 + r16) * 40 + grp * 8);
        bh8 b0 = *(const bh8*)(wsm + (r16) * 40 + grp * 8);
        bh8 b1 = *(const bh8*)(wsm + (16 + r16) * 40 + grp * 8);
        bh8 b2 = *(const bh8*)(wsm + (32 + r16) * 40 + grp * 8);
        a0 = __builtin_amdgcn_mfma_f32_16x16x32_bf16(af, b0, a0, 0, 0, 0);
        a1 = __builtin_amdgcn_mfma_f32_16x16x32_bf16(af, b1, a1, 0, 0, 0);
        a2 = __builtin_amdgcn_mfma_f32_16x16x32_bf16(af, b2, a2, 0, 0, 0);
        __syncthreads();
    }
    const int jt = (i0 >> 5) + (w >> 1);
    const int kg = ((w & 1) << 1) + (grp >> 1);
    const int lanep = kg * 16 + r16;
    const int ebase = (grp & 1) * 4;
    unsigned short* bp = Bp2 + (size_t)jt * 1536 + lanep * 8 + ebase;
    {
        uint2 v;
        v.x = pack2(a0[0], a0[1]); v.y = pack2(a0[2], a0[3]); *(uint2*)(bp + 0 * 512) = v;
        v.x = pack2(a1[0], a1[1]); v.y = pack2(a1[2], a1[3]); *(uint2*)(bp + 1 * 512) = v;
        v.x = pack2(a2[0], a2[1]); v.y = pack2(a2[2], a2[3]); *(uint2*)(bp + 2 * 512) = v;
    }
    float a1v[3], a2v[3];
#pragma unroll
    for (int n = 0; n < 3; ++n) {
        int col = r16 + 16 * n;
        a1v[n] = col < NCLS ? a_out[col] : 0.f;
        a2v[n] = col < NCLS ? a_out[NCLS + col] : 0.f;
    }
    float wmax = -3.0e38f;
#pragma unroll
    for (int r = 0; r < 4; ++r) {
        const int orow = i0 + w * 16 + grp * 4 + r;
        float s1 = a0[r] * a1v[0] + a1[r] * a1v[1] + a2[r] * a1v[2];
        float s2 = a0[r] * a2v[0] + a1[r] * a2v[1] + a2[r] * a2v[2];
#pragma unroll
        for (int o2 = 1; o2 < 16; o2 <<= 1) { s1 += __shfl_xor(s1, o2); s2 += __shfl_xor(s2, o2); }
        s1 *= LOG2E; s2 *= LOG2E;
        if (r16 == 0) { f12L[orow] = s1; f22L[orow] = s2; }
        wmax = fmaxf(wmax, s2);
    }
    wmax = fmaxf(wmax, __shfl_xor(wmax, 16));
    wmax = fmaxf(wmax, __shfl_xor(wmax, 32));
    if (lane == 0) atomicMax(&FM2u[0], fenc(wmax));
}

// ---------------- attn layer 1: 8 waves = 4 rowg x 2 j-halves, LDS combine ----------------
__global__ __launch_bounds__(512, 4) void attn1_k(const unsigned short* __restrict__ Bp1,
                                                  const unsigned char* __restrict__ adjp,
                                                  const float* __restrict__ f1L,
                                                  const float* __restrict__ f2L,
                                                  const unsigned* __restrict__ FM1u,
                                                  unsigned short* __restrict__ x2b) {
    __shared__ float comb[4][64][20];
    const int tid = threadIdx.x, w = tid >> 6, lane = tid & 63;
    const int r16 = lane & 15, grp = lane >> 4;
    const int rowg = w & 3, jq = w >> 2;
    const int h = blockIdx.y;
    const int i0 = blockIdx.x * 64;
    const int irow = i0 + rowg * 16 + r16;
    const float f1v = f1L[h * NN + irow];
    const float fm = fdec(FM1u[h]);
    const float mL = lrelu(f1v + fm);
    const float c1 = f1v - mL;
    const float c2 = __builtin_fmaf(0.2f, f1v, -mL);
    const float* f2p = f2L + h * NN;
    const unsigned char* adjr = adjp + ((size_t)irow * 4 + grp) * 128 + jq * 64;
    const unsigned short* Bbase = Bp1 + (size_t)h * 128 * 2048 + lane * 8;
    f32x4 acc0 = {0,0,0,0}, acc1 = {0,0,0,0}, acc2 = {0,0,0,0}, acc3 = {0,0,0,0}, accd = {0,0,0,0};
    const short ov = (r16 == 0) ? (short)0x3F80 : (short)0;
    bh8 ones;
#pragma unroll
    for (int e = 0; e < 8; ++e) ones[e] = ov;
    bh8 nb0, nb1, nb2, nb3;
    float4 nfa, nfb;
#define PREF1(JT) { const unsigned short* Bn = Bbase + (size_t)(JT) * 2048;              \
        nb0 = *(const bh8*)(Bn);        nb1 = *(const bh8*)(Bn + 512);                    \
        nb2 = *(const bh8*)(Bn + 1024); nb3 = *(const bh8*)(Bn + 1536);                   \
        nfa = *(const float4*)(f2p + (JT) * 32 + grp * 8);                                \
        nfb = *(const float4*)(f2p + (JT) * 32 + grp * 8 + 4); }
    const int jtbase = jq * 64;
    PREF1(jtbase);
    for (int jt4 = 0; jt4 < 16; ++jt4) {
        const unsigned mdw = *(const unsigned*)(adjr + jt4 * 4);
#pragma unroll
        for (int u = 0; u < 4; ++u) {
            const int jt = jtbase + jt4 * 4 + u;
            bh8 b0 = nb0, b1 = nb1, b2 = nb2, b3 = nb3;
            float4 fa = nfa, fb = nfb;
            PREF1(jt + 1);
            float fe[8] = {fa.x, fa.y, fa.z, fa.w, fb.x, fb.y, fb.z, fb.w};
            union { bh8 v; unsigned u32[4]; } pk;
#pragma unroll
            for (int e2 = 0; e2 < 4; ++e2) {
                float p0 = maskp(scoref(fe[2 * e2], c1, c2), mdw, u * 8 + 2 * e2);
                float p1 = maskp(scoref(fe[2 * e2 + 1], c1, c2), mdw, u * 8 + 2 * e2 + 1);
                pk.u32[e2] = __builtin_amdgcn_perm(__builtin_bit_cast(unsigned, p1),
                                                   __builtin_bit_cast(unsigned, p0), 0x07060302u);
            }
            acc0 = __builtin_amdgcn_mfma_f32_16x16x32_bf16(pk.v, b0, acc0, 0, 0, 0);
            acc1 = __builtin_amdgcn_mfma_f32_16x16x32_bf16(pk.v, b1, acc1, 0, 0, 0);
            acc2 = __builtin_amdgcn_mfma_f32_16x16x32_bf16(pk.v, b2, acc2, 0, 0, 0);
            acc3 = __builtin_amdgcn_mfma_f32_16x16x32_bf16(pk.v, b3, acc3, 0, 0, 0);
            accd = __builtin_amdgcn_mfma_f32_16x16x32_bf16(pk.v, ones, accd, 0, 0, 0);
        }
    }
#undef PREF1
    if (jq == 1) {
        float* cb = &comb[rowg][lane][0];
#pragma unroll
        for (int r = 0; r < 4; ++r) {
            cb[r] = acc0[r]; cb[4 + r] = acc1[r]; cb[8 + r] = acc2[r];
            cb[12 + r] = acc3[r]; cb[16 + r] = accd[r];
        }
    }
    __syncthreads();
    if (jq == 0) {
        const float* cb = &comb[rowg][lane][0];
#pragma unroll
        for (int r = 0; r < 4; ++r) {
            acc0[r] += cb[r]; acc1[r] += cb[4 + r]; acc2[r] += cb[8 + r];
            acc3[r] += cb[12 + r]; accd[r] += cb[16 + r];
        }
#pragma unroll
        for (int r = 0; r < 4; ++r) {
            const float den = __shfl(accd[r], lane & 48);
            const float inv = 1.0f / den;
            unsigned short* o = x2b + (size_t)(i0 + rowg * 16 + grp * 4 + r) * NF + h * 64 + r16;
            o[0]  = f2bu(elu1(acc0[r] * inv));
            o[16] = f2bu(elu1(acc1[r] * inv));
            o[32] = f2bu(elu1(acc2[r] * inv));
            o[48] = f2bu(elu1(acc3[r] * inv));
        }
    }
}

// ---------------- attn layer 2 partial: grid (64 i-blocks, 16 j-chunks) ----------------
__global__ __launch_bounds__(256) void attn2_k(const unsigned short* __restrict__ Bp2,
                                               const unsigned char* __restrict__ adjp,
                                               const float* __restrict__ f12L,
                                               const float* __restrict__ f22L,
                                               const unsigned* __restrict__ FM2u,
                                               float* __restrict__ Pa2) {
    const int tid = threadIdx.x, w = tid >> 6, lane = tid & 63;
    const int r16 = lane & 15, grp = lane >> 4;
    const int ch = blockIdx.y;
    const int i0 = blockIdx.x * 64 + w * 16;
    const int i = i0 + r16;
    const float f1v = f12L[i];
    const float mL = lrelu(f1v + fdec(FM2u[0]));
    const float c1 = f1v - mL;
    const float c2 = __builtin_fmaf(0.2f, f1v, -mL);
    const unsigned char* adjr = adjp + ((size_t)i * 4 + grp) * 128;
    f32x4 acc0 = {0,0,0,0}, acc1 = {0,0,0,0}, acc2 = {0,0,0,0}, accd = {0,0,0,0};
    const short ov = (r16 == 0) ? (short)0x3F80 : (short)0;
    bh8 ones;
#pragma unroll
    for (int e = 0; e < 8; ++e) ones[e] = ov;
    const int jt0 = ch * 8;
    const unsigned short* Bbase = Bp2 + lane * 8;
    bh8 nb0, nb1, nb2;
    float4 nfa, nfb;
#define PREF2(JT) { const unsigned short* Bn = Bbase + (size_t)(JT) * 1536;              \
        nb0 = *(const bh8*)(Bn); nb1 = *(const bh8*)(Bn + 512); nb2 = *(const bh8*)(Bn + 1024); \
        nfa = *(const float4*)(f22L + (JT) * 32 + grp * 8);                               \
        nfb = *(const float4*)(f22L + (JT) * 32 + grp * 8 + 4); }
    PREF2(jt0);
    for (int jt4 = 0; jt4 < 2; ++jt4) {
        const unsigned mdw = *(const unsigned*)(adjr + jt0 + jt4 * 4);
#pragma unroll
        for (int u = 0; u < 4; ++u) {
            const int jt = jt0 + jt4 * 4 + u;
            bh8 b0 = nb0, b1 = nb1, b2 = nb2;
            float4 fa = nfa, fb = nfb;
            PREF2(jt + 1);
            float fe[8] = {fa.x, fa.y, fa.z, fa.w, fb.x, fb.y, fb.z, fb.w};
            union { bh8 v; unsigned u32[4]; } pk;
#pragma unroll
            for (int e2 = 0; e2 < 4; ++e2) {
                float p0 = maskp(scoref(fe[2 * e2], c1, c2), mdw, u * 8 + 2 * e2);
                float p1 = maskp(scoref(fe[2 * e2 + 1], c1, c2), mdw, u * 8 + 2 * e2 + 1);
                pk.u32[e2] = __builtin_amdgcn_perm(__builtin_bit_cast(unsigned, p1),
                                                   __builtin_bit_cast(unsigned, p0), 0x07060302u);
            }
            acc0 = __builtin_amdgcn_mfma_f32_16x16x32_bf16(pk.v, b0, acc0, 0, 0, 0);
            acc1 = __builtin_amdgcn_mfma_f32_16x16x32_bf16(pk.v, b1, acc1, 0, 0, 0);
            acc2 = __builtin_amdgcn_mfma_f32_16x16x32_bf16(pk.v, b2, acc2, 0, 0, 0);
            accd = __builtin_amdgcn_mfma_f32_16x16x32_bf16(pk.v, ones, accd, 0, 0, 0);
        }
    }
#undef PREF2
#pragma unroll
    for (int r = 0; r < 4; ++r) {
        const int row = i0 + grp * 4 + r;
        float* prow = Pa2 + ((size_t)ch * NN + row) * 52;
        prow[r16] = acc0[r];
        prow[16 + r16] = acc1[r];
        prow[32 + r16] = acc2[r];
        if (r16 == 0) prow[48] = accd[r];
    }
}

// ---------------- attn2 finish: reduce chunks, elu, log_softmax ----------------
__global__ __launch_bounds__(256) void attn2fin_k(const float* __restrict__ Pa2,
                                                  float* __restrict__ out) {
    const int tid = threadIdx.x;
    const int row = blockIdx.x * 4 + (tid >> 6);
    const int lane = tid & 63;
    float s = 0.f;
    if (lane < 49) {
#pragma unroll
        for (int c = 0; c < 16; ++c) s += Pa2[((size_t)c * NN + row) * 52 + lane];
    }
    const float den = __shfl(s, 48);
    const float inv = 1.0f / den;
    float v = (lane < NCLS) ? elu1(s * inv) : -3.0e38f;
    float mx = v;
#pragma unroll
    for (int o = 1; o < 64; o <<= 1) mx = fmaxf(mx, __shfl_xor(mx, o));
    float ex = (lane < NCLS) ? __expf(v - mx) : 0.f;
#pragma unroll
    for (int o = 1; o < 64; o <<= 1) ex += __shfl_xor(ex, o);
    const float lse = mx + logf(ex);
    if (lane < NCLS) out[(size_t)row * NCLS + lane] = v - lse;
}

// ---------------- workspace layout (bytes) ----------------
#define OFF_XB   0ULL           // 4096*512*2 = 4194304
#define OFF_WT   4194304ULL     // 512*512*2  = 524288
#define OFF_WOT  4718592ULL     // 48*512*2   = 49152
#define OFF_BP1  4767744ULL     // 8*128*2048*2 = 4194304
#define OFF_X2B  8962048ULL     // 4096*512*2 = 4194304
#define OFF_BP2  13156352ULL    // 128*1536*2 = 393216
#define OFF_F1L  13549568ULL    // 8*4096*4 = 131072
#define OFF_F2L  13680640ULL    // 131072
#define OFF_F12  13811712ULL    // 16384
#define OFF_F22  13828096ULL    // 16384
#define OFF_FM1  13844480ULL    // 256
#define OFF_FM2  13844736ULL    // 256
#define OFF_ADJ  13844992ULL    // 4096*4*128 = 2097152
#define OFF_PA2  15942144ULL    // 16*4096*52*4 = 13631488 -> end 29573632

extern "C" void kernel_launch(void* const* d_in, const int* in_sizes, int n_in,
                              void* d_out, int out_size, void* d_ws, size_t ws_size,
                              hipStream_t stream) {
    const float* x     = (const float*)d_in[0];
    const float* adj   = (const float*)d_in[1];
    const float* Ws    = (const float*)d_in[2];
    const float* a_s   = (const float*)d_in[3];
    const float* W_out = (const float*)d_in[4];
    const float* a_out = (const float*)d_in[5];
    float* out = (float*)d_out;
    char* w = (char*)d_ws;

    unsigned short* xb  = (unsigned short*)(w + OFF_XB);
    unsigned short* WT  = (unsigned short*)(w + OFF_WT);
    unsigned short* WoT = (unsigned short*)(w + OFF_WOT);
    unsigned short* Bp1 = (unsigned short*)(w + OFF_BP1);
    unsigned short* x2b = (unsigned short*)(w + OFF_X2B);
    unsigned short* Bp2 = (unsigned short*)(w + OFF_BP2);
    float* f1L = (float*)(w + OFF_F1L);
    float* f2L = (float*)(w + OFF_F2L);
    float* f12 = (float*)(w + OFF_F12);
    float* f22 = (float*)(w + OFF_F22);
    unsigned* FM1u = (unsigned*)(w + OFF_FM1);
    unsigned* FM2u = (unsigned*)(w + OFF_FM2);
    unsigned char* adjp = (unsigned char*)(w + OFF_ADJ);
    float* Pa2 = (float*)(w + OFF_PA2);

    prep_xb_k<<<8192, 256, 0, stream>>>(x, xb);
    prep_W_k<<<1120, 256, 0, stream>>>(Ws, W_out, WT, WoT);
    prep_adj_k<<<1024, 256, 0, stream>>>(adj, adjp, FM1u, FM2u);

    gemm1_k<<<dim3(64, 8), 256, 0, stream>>>(xb, WT, a_s, Bp1, f1L, f2L, FM1u);
    attn1_k<<<dim3(64, 8), 512, 0, stream>>>(Bp1, adjp, f1L, f2L, FM1u, x2b);

    gemm2_k<<<64, 256, 0, stream>>>(x2b, WoT, a_out, Bp2, f12, f22, FM2u);
    attn2_k<<<dim3(64, 16), 256, 0, stream>>>(Bp2, adjp, f12, f22, FM2u, Pa2);
    attn2fin_k<<<1024, 256, 0, stream>>>(Pa2, out);
}

// Round 5
// 233.297 us; speedup vs baseline: 1.7561x; 1.1173x over previous
//
#include <hip/hip_runtime.h>
#include <hip/hip_bf16.h>
#include <stdint.h>

#define NN 4096      // nodes
#define NF 512       // NFEAT = NHEADS*NHID
#define NH 64        // NHID
#define NCLS 40      // NCLASS
#define NHEADS 8
#define LOG2E 1.4426950408889634f

typedef __attribute__((ext_vector_type(8))) short bh8;
typedef __attribute__((ext_vector_type(4))) float f32x4;

__device__ __forceinline__ unsigned short f2bu(float f) {
    union { float f; unsigned u; } v; v.f = f;
    unsigned r = (v.u + 0x7FFFu + ((v.u >> 16) & 1u)) >> 16;
    return (unsigned short)r;
}
__device__ __forceinline__ float lrelu(float x) { return fmaxf(x, 0.2f * x); }
__device__ __forceinline__ float elu1(float x) { return x > 0.f ? x : expm1f(x); }
__device__ __forceinline__ float exp2fast(float x) {
    float r; asm("v_exp_f32 %0, %1" : "=v"(r) : "v"(x)); return r;
}
// ordered-uint encode/decode for float atomicMax
__device__ __forceinline__ unsigned fenc(float f) {
    unsigned u = __builtin_bit_cast(unsigned, f);
    return ((int)u < 0) ? ~u : (u | 0x80000000u);
}
__device__ __forceinline__ float fdec(unsigned k) {
    unsigned u = (k & 0x80000000u) ? (k ^ 0x80000000u) : ~k;
    return __builtin_bit_cast(float, u);
}
// 1-bit sign-extended field extract: 0 or 0xFFFFFFFF
__device__ __forceinline__ int sbfe1(unsigned v, int off) {
#if __has_builtin(__builtin_amdgcn_sbfe)
    return __builtin_amdgcn_sbfe((int)v, off, 1);
#else
    return ((int)(v << (31 - off))) >> 31;
#endif
}
__device__ __forceinline__ float bmask(float p, unsigned mdw, int bit) {
    return __builtin_bit_cast(float,
        __builtin_bit_cast(unsigned, p) & (unsigned)sbfe1(mdw, bit));
}

// ---------------- prep: x->bf16, W transposes (merged) ----------------
__global__ void prep_all_k(const float* __restrict__ x, const float* __restrict__ Ws,
                           const float* __restrict__ Wo,
                           unsigned short* __restrict__ xb, unsigned short* __restrict__ WT,
                           unsigned short* __restrict__ WoT) {
    int idx = blockIdx.x * 256 + threadIdx.x;
    if (idx < 2097152) {
        xb[idx] = f2bu(x[idx]);
    } else if (idx < 2097152 + 262144) {
        int j = idx - 2097152;
        int c = j >> 9, k = j & 511;
        WT[j] = f2bu(Ws[(size_t)(c >> 6) * (NF * NH) + (size_t)k * NH + (c & 63)]);
    } else if (idx < 2097152 + 262144 + 24576) {
        int j = idx - 2359296;
        int c = j >> 9, k = j & 511;
        WoT[j] = f2bu(c < NCLS ? Wo[(size_t)k * NCLS + c] : 0.f);
    }
}
// adjacency -> byte planes + FM init
__global__ __launch_bounds__(256) void prep_adj_k(const float* __restrict__ adj,
                                                  unsigned char* __restrict__ adjp,
                                                  unsigned* __restrict__ FM1u,
                                                  unsigned* __restrict__ FM2u) {
    if (blockIdx.x == 0) {
        if (threadIdx.x < 8) FM1u[threadIdx.x] = 0u;
        if (threadIdx.x == 8) FM2u[0] = 0u;
    }
    int w = threadIdx.x >> 6, lane = threadIdx.x & 63;
    int i = blockIdx.x * 4 + w;
    const float* row = adj + (size_t)i * NN;
    for (int t = 0; t < 64; ++t) {
        uint64_t m = __ballot(row[t * 64 + lane] > 0.f);
        if (lane < 8) {
            unsigned char mb = (unsigned char)(m >> (8 * lane));
            int grp = lane & 3, jt = 2 * t + (lane >> 2);
            adjp[((size_t)i * 4 + grp) * 128 + jt] = mb;
        }
    }
}

// pack two f32 -> bf16 pair (RN)
__device__ __forceinline__ unsigned pack2(float x, float y) {
    unsigned ux = __builtin_bit_cast(unsigned, x), uy = __builtin_bit_cast(unsigned, y);
    ux += 0x7FFFu + ((ux >> 16) & 1u);
    uy += 0x7FFFu + ((uy >> 16) & 1u);
    return __builtin_amdgcn_perm(uy, ux, 0x07060302u);
}

// ---------------- GEMM1: Bp1 = pack(x @ Wcat), f1/f2 + FM1 epilogue ----------------
__global__ __launch_bounds__(256) void gemm1_k(const unsigned short* __restrict__ xb,
                                               const unsigned short* __restrict__ WT,
                                               const float* __restrict__ a_s,
                                               unsigned short* __restrict__ Bp1,
                                               float* __restrict__ f1L,
                                               float* __restrict__ f2L,
                                               unsigned* __restrict__ FM1u) {
    __shared__ unsigned short xs[64 * 40];
    __shared__ unsigned short wsm[64 * 40];
    const int tid = threadIdx.x;
    const int w = tid >> 6, lane = tid & 63, r16 = lane & 15, grp = lane >> 4;
    const int i0 = blockIdx.x << 6, h = blockIdx.y, c0 = h << 6;
    const int srow = tid >> 2, sseg = tid & 3;
    const unsigned short* xsrc = xb + (size_t)(i0 + srow) * NF + sseg * 8;
    const unsigned short* wsrc = WT + (size_t)(c0 + srow) * NF + sseg * 8;
    f32x4 a0 = {0,0,0,0}, a1 = {0,0,0,0}, a2 = {0,0,0,0}, a3 = {0,0,0,0};
    bh8 rx = *(const bh8*)(xsrc), rw = *(const bh8*)(wsrc);
    for (int kb = 0; kb < NF; kb += 32) {
        *(bh8*)(xs + srow * 40 + sseg * 8) = rx;
        *(bh8*)(wsm + srow * 40 + sseg * 8) = rw;
        __syncthreads();
        if (kb + 32 < NF) { rx = *(const bh8*)(xsrc + kb + 32); rw = *(const bh8*)(wsrc + kb + 32); }
        bh8 af = *(const bh8*)(xs + (w * 16 + r16) * 40 + grp * 8);
        bh8 b0 = *(const bh8*)(wsm + (r16) * 40 + grp * 8);
        bh8 b1 = *(const bh8*)(wsm + (16 + r16) * 40 + grp * 8);
        bh8 b2 = *(const bh8*)(wsm + (32 + r16) * 40 + grp * 8);
        bh8 b3 = *(const bh8*)(wsm + (48 + r16) * 40 + grp * 8);
        a0 = __builtin_amdgcn_mfma_f32_16x16x32_bf16(af, b0, a0, 0, 0, 0);
        a1 = __builtin_amdgcn_mfma_f32_16x16x32_bf16(af, b1, a1, 0, 0, 0);
        a2 = __builtin_amdgcn_mfma_f32_16x16x32_bf16(af, b2, a2, 0, 0, 0);
        a3 = __builtin_amdgcn_mfma_f32_16x16x32_bf16(af, b3, a3, 0, 0, 0);
        __syncthreads();
    }
    // direct B-panel write: Bp1[h][jt][n][lane'][e]
    const int jt = (i0 >> 5) + (w >> 1);
    const int kg = ((w & 1) << 1) + (grp >> 1);
    const int lanep = kg * 16 + r16;
    const int ebase = (grp & 1) * 4;
    unsigned short* bp = Bp1 + ((size_t)(h * 128 + jt)) * 2048 + lanep * 8 + ebase;
    {
        uint2 v;
        v.x = pack2(a0[0], a0[1]); v.y = pack2(a0[2], a0[3]); *(uint2*)(bp + 0 * 512) = v;
        v.x = pack2(a1[0], a1[1]); v.y = pack2(a1[2], a1[3]); *(uint2*)(bp + 1 * 512) = v;
        v.x = pack2(a2[0], a2[1]); v.y = pack2(a2[2], a2[3]); *(uint2*)(bp + 2 * 512) = v;
        v.x = pack2(a3[0], a3[1]); v.y = pack2(a3[2], a3[3]); *(uint2*)(bp + 3 * 512) = v;
    }
    const float* ap = a_s + h * 128;
    float a1v[4], a2v[4];
#pragma unroll
    for (int n = 0; n < 4; ++n) { a1v[n] = ap[r16 + 16 * n]; a2v[n] = ap[64 + r16 + 16 * n]; }
    float wmax = -3.0e38f;
#pragma unroll
    for (int r = 0; r < 4; ++r) {
        const int orow = i0 + w * 16 + grp * 4 + r;
        float s1 = a0[r] * a1v[0] + a1[r] * a1v[1] + a2[r] * a1v[2] + a3[r] * a1v[3];
        float s2 = a0[r] * a2v[0] + a1[r] * a2v[1] + a2[r] * a2v[2] + a3[r] * a2v[3];
#pragma unroll
        for (int o2 = 1; o2 < 16; o2 <<= 1) { s1 += __shfl_xor(s1, o2); s2 += __shfl_xor(s2, o2); }
        s1 *= LOG2E; s2 *= LOG2E;
        if (r16 == 0) { f1L[h * NN + orow] = s1; f2L[h * NN + orow] = s2; }
        wmax = fmaxf(wmax, s2);
    }
    wmax = fmaxf(wmax, __shfl_xor(wmax, 16));
    wmax = fmaxf(wmax, __shfl_xor(wmax, 32));
    if (lane == 0) atomicMax(&FM1u[h], fenc(wmax));
}

// ---------------- GEMM2: Bp2 = pack(x2 @ W_out), f12/f22 + FM2 epilogue ----------------
__global__ __launch_bounds__(256) void gemm2_k(const unsigned short* __restrict__ x2b,
                                               const unsigned short* __restrict__ WoT,
                                               const float* __restrict__ a_out,
                                               unsigned short* __restrict__ Bp2,
                                               float* __restrict__ f12L,
                                               float* __restrict__ f22L,
                                               unsigned* __restrict__ FM2u) {
    __shared__ unsigned short xs[64 * 40];
    __shared__ unsigned short wsm[48 * 40];
    const int tid = threadIdx.x;
    const int w = tid >> 6, lane = tid & 63, r16 = lane & 15, grp = lane >> 4;
    const int i0 = blockIdx.x << 6;
    const int srow = tid >> 2, sseg = tid & 3;
    const unsigned short* xsrc = x2b + (size_t)(i0 + srow) * NF + sseg * 8;
    const unsigned short* wsrc = WoT + (size_t)srow * NF + sseg * 8;
    f32x4 a0 = {0,0,0,0}, a1 = {0,0,0,0}, a2 = {0,0,0,0};
    bh8 rx = *(const bh8*)(xsrc);
    bh8 rw; if (tid < 192) rw = *(const bh8*)(wsrc);
    for (int kb = 0; kb < NF; kb += 32) {
        *(bh8*)(xs + srow * 40 + sseg * 8) = rx;
        if (tid < 192) *(bh8*)(wsm + srow * 40 + sseg * 8) = rw;
        __syncthreads();
        if (kb + 32 < NF) {
            rx = *(const bh8*)(xsrc + kb + 32);
            if (tid < 192) rw = *(const bh8*)(wsrc + kb + 32);
        }
        bh8 af = *(const bh8*)(xs + (w * 16 + r16) * 40 + grp * 8);
        bh8 b0 = *(const bh8*)(wsm + (r16) * 40 + grp * 8);
        bh8 b1 = *(const bh8*)(wsm + (16 + r16) * 40 + grp * 8);
        bh8 b2 = *(const bh8*)(wsm + (32 + r16) * 40 + grp * 8);
        a0 = __builtin_amdgcn_mfma_f32_16x16x32_bf16(af, b0, a0, 0, 0, 0);
        a1 = __builtin_amdgcn_mfma_f32_16x16x32_bf16(af, b1, a1, 0, 0, 0);
        a2 = __builtin_amdgcn_mfma_f32_16x16x32_bf16(af, b2, a2, 0, 0, 0);
        __syncthreads();
    }
    const int jt = (i0 >> 5) + (w >> 1);
    const int kg = ((w & 1) << 1) + (grp >> 1);
    const int lanep = kg * 16 + r16;
    const int ebase = (grp & 1) * 4;
    unsigned short* bp = Bp2 + (size_t)jt * 1536 + lanep * 8 + ebase;
    {
        uint2 v;
        v.x = pack2(a0[0], a0[1]); v.y = pack2(a0[2], a0[3]); *(uint2*)(bp + 0 * 512) = v;
        v.x = pack2(a1[0], a1[1]); v.y = pack2(a1[2], a1[3]); *(uint2*)(bp + 1 * 512) = v;
        v.x = pack2(a2[0], a2[1]); v.y = pack2(a2[2], a2[3]); *(uint2*)(bp + 2 * 512) = v;
    }
    float a1v[3], a2v[3];
#pragma unroll
    for (int n = 0; n < 3; ++n) {
        int col = r16 + 16 * n;
        a1v[n] = col < NCLS ? a_out[col] : 0.f;
        a2v[n] = col < NCLS ? a_out[NCLS + col] : 0.f;
    }
    float wmax = -3.0e38f;
#pragma unroll
    for (int r = 0; r < 4; ++r) {
        const int orow = i0 + w * 16 + grp * 4 + r;
        float s1 = a0[r] * a1v[0] + a1[r] * a1v[1] + a2[r] * a1v[2];
        float s2 = a0[r] * a2v[0] + a1[r] * a2v[1] + a2[r] * a2v[2];
#pragma unroll
        for (int o2 = 1; o2 < 16; o2 <<= 1) { s1 += __shfl_xor(s1, o2); s2 += __shfl_xor(s2, o2); }
        s1 *= LOG2E; s2 *= LOG2E;
        if (r16 == 0) { f12L[orow] = s1; f22L[orow] = s2; }
        wmax = fmaxf(wmax, s2);
    }
    wmax = fmaxf(wmax, __shfl_xor(wmax, 16));
    wmax = fmaxf(wmax, __shfl_xor(wmax, 32));
    if (lane == 0) atomicMax(&FM2u[0], fenc(wmax));
}

// ---------------- attn layer 1: EF tables + adj in LDS, factored scores ----------------
__global__ __launch_bounds__(512, 4) void attn1_k(const unsigned short* __restrict__ Bp1,
                                                  const unsigned char* __restrict__ adjp,
                                                  const float* __restrict__ f1L,
                                                  const float* __restrict__ f2L,
                                                  const unsigned* __restrict__ FM1u,
                                                  unsigned short* __restrict__ x2b) {
    __shared__ float EFs[8192];                 // 32 KiB: (E,F) pairs for 4096 j
    __shared__ unsigned ADJd[64 * 4 * 33];      // 33.8 KiB: adj bytes, 132B pitch
    const int tid = threadIdx.x, w = tid >> 6, lane = tid & 63;
    const int r16 = lane & 15, grp = lane >> 4;
    const int rowg = w & 3, jq = w >> 2;
    const int h = blockIdx.y;
    const int i0 = blockIdx.x * 64;
    const float fm = fdec(FM1u[h]);
    const float* f2p = f2L + h * NN;
    // stage EF (each thread 8 j's)
    for (int t = 0; t < 8; ++t) {
        int j = tid + t * 512;
        float d = f2p[j] - fm;
        EFs[2 * j] = exp2fast(d);
        EFs[2 * j + 1] = exp2fast(0.2f * d);
    }
    // stage adjacency rows [i0, i0+64) with 33-dword pitch
    {
        const unsigned* asrc = (const unsigned*)(adjp + (size_t)i0 * 512);
        for (int t = 0; t < 16; ++t) {
            int idx = tid + t * 512;
            ADJd[(idx >> 5) * 33 + (idx & 31)] = asrc[idx];
        }
    }
    const int irow = i0 + rowg * 16 + r16;
    const float f1v = f1L[h * NN + irow];
    const float mL = lrelu(f1v + fm);
    const float A = exp2fast(f1v + fm - mL);
    const float B = exp2fast(__builtin_fmaf(0.2f, f1v + fm, -mL));
    __syncthreads();
    const unsigned* adjrd = ADJd + ((rowg * 16 + r16) * 4 + grp) * 33 + jq * 16;
    const float* efp = EFs + grp * 16;
    const unsigned short* Bbase = Bp1 + (size_t)h * 128 * 2048 + lane * 8;
    f32x4 acc0 = {0,0,0,0}, acc1 = {0,0,0,0}, acc2 = {0,0,0,0}, acc3 = {0,0,0,0}, accd = {0,0,0,0};
    const short ov = (r16 == 0) ? (short)0x3F80 : (short)0;
    bh8 ones;
#pragma unroll
    for (int e = 0; e < 8; ++e) ones[e] = ov;
    bh8 nb0, nb1, nb2, nb3;
#define PREF1(JT) { const unsigned short* Bn = Bbase + (size_t)(JT) * 2048;              \
        nb0 = *(const bh8*)(Bn);        nb1 = *(const bh8*)(Bn + 512);                    \
        nb2 = *(const bh8*)(Bn + 1024); nb3 = *(const bh8*)(Bn + 1536); }
    const int jtbase = jq * 64;
    PREF1(jtbase);
    for (int jt4 = 0; jt4 < 16; ++jt4) {
        const unsigned mdw = adjrd[jt4];
#pragma unroll
        for (int u = 0; u < 4; ++u) {
            const int jt = jtbase + jt4 * 4 + u;
            bh8 b0 = nb0, b1 = nb1, b2 = nb2, b3 = nb3;
            PREF1(jt + 1);
            const float* e4 = efp + jt * 64;
            float4 ea = *(const float4*)(e4);
            float4 eb = *(const float4*)(e4 + 4);
            float4 ec = *(const float4*)(e4 + 8);
            float4 ed = *(const float4*)(e4 + 12);
            const int bb = u * 8;
            union { bh8 v; unsigned u32[4]; } pk;
            {
                float p0 = bmask(fmaxf(A * ea.x, B * ea.y), mdw, bb + 0);
                float p1 = bmask(fmaxf(A * ea.z, B * ea.w), mdw, bb + 1);
                pk.u32[0] = __builtin_amdgcn_perm(__builtin_bit_cast(unsigned, p1),
                                                  __builtin_bit_cast(unsigned, p0), 0x07060302u);
                float p2 = bmask(fmaxf(A * eb.x, B * eb.y), mdw, bb + 2);
                float p3 = bmask(fmaxf(A * eb.z, B * eb.w), mdw, bb + 3);
                pk.u32[1] = __builtin_amdgcn_perm(__builtin_bit_cast(unsigned, p3),
                                                  __builtin_bit_cast(unsigned, p2), 0x07060302u);
                float p4 = bmask(fmaxf(A * ec.x, B * ec.y), mdw, bb + 4);
                float p5 = bmask(fmaxf(A * ec.z, B * ec.w), mdw, bb + 5);
                pk.u32[2] = __builtin_amdgcn_perm(__builtin_bit_cast(unsigned, p5),
                                                  __builtin_bit_cast(unsigned, p4), 0x07060302u);
                float p6 = bmask(fmaxf(A * ed.x, B * ed.y), mdw, bb + 6);
                float p7 = bmask(fmaxf(A * ed.z, B * ed.w), mdw, bb + 7);
                pk.u32[3] = __builtin_amdgcn_perm(__builtin_bit_cast(unsigned, p7),
                                                  __builtin_bit_cast(unsigned, p6), 0x07060302u);
            }
            acc0 = __builtin_amdgcn_mfma_f32_16x16x32_bf16(pk.v, b0, acc0, 0, 0, 0);
            acc1 = __builtin_amdgcn_mfma_f32_16x16x32_bf16(pk.v, b1, acc1, 0, 0, 0);
            acc2 = __builtin_amdgcn_mfma_f32_16x16x32_bf16(pk.v, b2, acc2, 0, 0, 0);
            acc3 = __builtin_amdgcn_mfma_f32_16x16x32_bf16(pk.v, b3, acc3, 0, 0, 0);
            accd = __builtin_amdgcn_mfma_f32_16x16x32_bf16(pk.v, ones, accd, 0, 0, 0);
        }
    }
#undef PREF1
    __syncthreads();                 // everyone done reading EFs/ADJd
    float (*comb)[64][20] = (float(*)[64][20])EFs;   // reuse LDS
    if (jq == 1) {
        float* cb = &comb[rowg][lane][0];
#pragma unroll
        for (int r = 0; r < 4; ++r) {
            cb[r] = acc0[r]; cb[4 + r] = acc1[r]; cb[8 + r] = acc2[r];
            cb[12 + r] = acc3[r]; cb[16 + r] = accd[r];
        }
    }
    __syncthreads();
    if (jq == 0) {
        const float* cb = &comb[rowg][lane][0];
#pragma unroll
        for (int r = 0; r < 4; ++r) {
            acc0[r] += cb[r]; acc1[r] += cb[4 + r]; acc2[r] += cb[8 + r];
            acc3[r] += cb[12 + r]; accd[r] += cb[16 + r];
        }
#pragma unroll
        for (int r = 0; r < 4; ++r) {
            const float den = __shfl(accd[r], lane & 48);
            const float inv = 1.0f / den;
            unsigned short* o = x2b + (size_t)(i0 + rowg * 16 + grp * 4 + r) * NF + h * 64 + r16;
            o[0]  = f2bu(elu1(acc0[r] * inv));
            o[16] = f2bu(elu1(acc1[r] * inv));
            o[32] = f2bu(elu1(acc2[r] * inv));
            o[48] = f2bu(elu1(acc3[r] * inv));
        }
    }
}

// ---------------- attn layer 2 partial: grid (64 i-blocks, 8 j-chunks) ----------------
__global__ __launch_bounds__(256, 4) void attn2_k(const unsigned short* __restrict__ Bp2,
                                                  const unsigned char* __restrict__ adjp,
                                                  const float* __restrict__ f12L,
                                                  const float* __restrict__ f22L,
                                                  const unsigned* __restrict__ FM2u,
                                                  float* __restrict__ Pa2) {
    __shared__ float EFs[1024];         // (E,F) for this chunk's 512 j
    const int tid = threadIdx.x, w = tid >> 6, lane = tid & 63;
    const int r16 = lane & 15, grp = lane >> 4;
    const int ch = blockIdx.y;
    const int i0 = blockIdx.x * 64 + w * 16;
    const int i = i0 + r16;
    const float fm = fdec(FM2u[0]);
    for (int t = 0; t < 2; ++t) {
        int j = tid + t * 256;
        float d = f22L[ch * 512 + j] - fm;
        EFs[2 * j] = exp2fast(d);
        EFs[2 * j + 1] = exp2fast(0.2f * d);
    }
    const float f1v = f12L[i];
    const float mL = lrelu(f1v + fm);
    const float A = exp2fast(f1v + fm - mL);
    const float B = exp2fast(__builtin_fmaf(0.2f, f1v + fm, -mL));
    __syncthreads();
    const unsigned char* adjr = adjp + ((size_t)i * 4 + grp) * 128 + ch * 16;
    f32x4 acc0 = {0,0,0,0}, acc1 = {0,0,0,0}, acc2 = {0,0,0,0}, accd = {0,0,0,0};
    const short ov = (r16 == 0) ? (short)0x3F80 : (short)0;
    bh8 ones;
#pragma unroll
    for (int e = 0; e < 8; ++e) ones[e] = ov;
    const int jt0 = ch * 16;
    const unsigned short* Bbase = Bp2 + lane * 8;
    const float* efp = EFs + grp * 16;
    bh8 nb0, nb1, nb2;
#define PREF2(JT) { const unsigned short* Bn = Bbase + (size_t)(JT) * 1536;              \
        nb0 = *(const bh8*)(Bn); nb1 = *(const bh8*)(Bn + 512); nb2 = *(const bh8*)(Bn + 1024); }
    PREF2(jt0);
    for (int jt4 = 0; jt4 < 4; ++jt4) {
        const unsigned mdw = *(const unsigned*)(adjr + jt4 * 4);
#pragma unroll
        for (int u = 0; u < 4; ++u) {
            const int ltj = jt4 * 4 + u;
            bh8 b0 = nb0, b1 = nb1, b2 = nb2;
            PREF2(jt0 + ltj + 1);
            const float* e4 = efp + ltj * 64;
            float4 ea = *(const float4*)(e4);
            float4 eb = *(const float4*)(e4 + 4);
            float4 ec = *(const float4*)(e4 + 8);
            float4 ed = *(const float4*)(e4 + 12);
            const int bb = u * 8;
            union { bh8 v; unsigned u32[4]; } pk;
            {
                float p0 = bmask(fmaxf(A * ea.x, B * ea.y), mdw, bb + 0);
                float p1 = bmask(fmaxf(A * ea.z, B * ea.w), mdw, bb + 1);
                pk.u32[0] = __builtin_amdgcn_perm(__builtin_bit_cast(unsigned, p1),
                                                  __builtin_bit_cast(unsigned, p0), 0x07060302u);
                float p2 = bmask(fmaxf(A * eb.x, B * eb.y), mdw, bb + 2);
                float p3 = bmask(fmaxf(A * eb.z, B * eb.w), mdw, bb + 3);
                pk.u32[1] = __builtin_amdgcn_perm(__builtin_bit_cast(unsigned, p3),
                                                  __builtin_bit_cast(unsigned, p2), 0x07060302u);
                float p4 = bmask(fmaxf(A * ec.x, B * ec.y), mdw, bb + 4);
                float p5 = bmask(fmaxf(A * ec.z, B * ec.w), mdw, bb + 5);
                pk.u32[2] = __builtin_amdgcn_perm(__builtin_bit_cast(unsigned, p5),
                                                  __builtin_bit_cast(unsigned, p4), 0x07060302u);
                float p6 = bmask(fmaxf(A * ed.x, B * ed.y), mdw, bb + 6);
                float p7 = bmask(fmaxf(A * ed.z, B * ed.w), mdw, bb + 7);
                pk.u32[3] = __builtin_amdgcn_perm(__builtin_bit_cast(unsigned, p7),
                                                  __builtin_bit_cast(unsigned, p6), 0x07060302u);
            }
            acc0 = __builtin_amdgcn_mfma_f32_16x16x32_bf16(pk.v, b0, acc0, 0, 0, 0);
            acc1 = __builtin_amdgcn_mfma_f32_16x16x32_bf16(pk.v, b1, acc1, 0, 0, 0);
            acc2 = __builtin_amdgcn_mfma_f32_16x16x32_bf16(pk.v, b2, acc2, 0, 0, 0);
            accd = __builtin_amdgcn_mfma_f32_16x16x32_bf16(pk.v, ones, accd, 0, 0, 0);
        }
    }
#undef PREF2
#pragma unroll
    for (int r = 0; r < 4; ++r) {
        const int row = i0 + grp * 4 + r;
        float* prow = Pa2 + ((size_t)ch * NN + row) * 52;
        prow[r16] = acc0[r];
        prow[16 + r16] = acc1[r];
        prow[32 + r16] = acc2[r];
        if (r16 == 0) prow[48] = accd[r];
    }
}

// ---------------- attn2 finish: reduce chunks, elu, log_softmax ----------------
__global__ __launch_bounds__(256) void attn2fin_k(const float* __restrict__ Pa2,
                                                  float* __restrict__ out) {
    const int tid = threadIdx.x;
    const int row = blockIdx.x * 4 + (tid >> 6);
    const int lane = tid & 63;
    float s = 0.f;
    if (lane < 49) {
#pragma unroll
        for (int c = 0; c < 8; ++c) s += Pa2[((size_t)c * NN + row) * 52 + lane];
    }
    const float den = __shfl(s, 48);
    const float inv = 1.0f / den;
    float v = (lane < NCLS) ? elu1(s * inv) : -3.0e38f;
    float mx = v;
#pragma unroll
    for (int o = 1; o < 64; o <<= 1) mx = fmaxf(mx, __shfl_xor(mx, o));
    float ex = (lane < NCLS) ? __expf(v - mx) : 0.f;
#pragma unroll
    for (int o = 1; o < 64; o <<= 1) ex += __shfl_xor(ex, o);
    const float lse = mx + logf(ex);
    if (lane < NCLS) out[(size_t)row * NCLS + lane] = v - lse;
}

// ---------------- workspace layout (bytes) ----------------
#define OFF_XB   0ULL           // 4096*512*2 = 4194304
#define OFF_WT   4194304ULL     // 512*512*2  = 524288
#define OFF_WOT  4718592ULL     // 48*512*2   = 49152
#define OFF_BP1  4767744ULL     // 8*128*2048*2 = 4194304
#define OFF_X2B  8962048ULL     // 4096*512*2 = 4194304
#define OFF_BP2  13156352ULL    // 128*1536*2 = 393216
#define OFF_F1L  13549568ULL    // 8*4096*4 = 131072
#define OFF_F2L  13680640ULL    // 131072
#define OFF_F12  13811712ULL    // 16384
#define OFF_F22  13828096ULL    // 16384
#define OFF_FM1  13844480ULL    // 256
#define OFF_FM2  13844736ULL    // 256
#define OFF_ADJ  13844992ULL    // 4096*4*128 = 2097152
#define OFF_PA2  15942144ULL    // 8*4096*52*4 = 6815744 -> end 22757888

extern "C" void kernel_launch(void* const* d_in, const int* in_sizes, int n_in,
                              void* d_out, int out_size, void* d_ws, size_t ws_size,
                              hipStream_t stream) {
    const float* x     = (const float*)d_in[0];
    const float* adj   = (const float*)d_in[1];
    const float* Ws    = (const float*)d_in[2];
    const float* a_s   = (const float*)d_in[3];
    const float* W_out = (const float*)d_in[4];
    const float* a_out = (const float*)d_in[5];
    float* out = (float*)d_out;
    char* w = (char*)d_ws;

    unsigned short* xb  = (unsigned short*)(w + OFF_XB);
    unsigned short* WT  = (unsigned short*)(w + OFF_WT);
    unsigned short* WoT = (unsigned short*)(w + OFF_WOT);
    unsigned short* Bp1 = (unsigned short*)(w + OFF_BP1);
    unsigned short* x2b = (unsigned short*)(w + OFF_X2B);
    unsigned short* Bp2 = (unsigned short*)(w + OFF_BP2);
    float* f1L = (float*)(w + OFF_F1L);
    float* f2L = (float*)(w + OFF_F2L);
    float* f12 = (float*)(w + OFF_F12);
    float* f22 = (float*)(w + OFF_F22);
    unsigned* FM1u = (unsigned*)(w + OFF_FM1);
    unsigned* FM2u = (unsigned*)(w + OFF_FM2);
    unsigned char* adjp = (unsigned char*)(w + OFF_ADJ);
    float* Pa2 = (float*)(w + OFF_PA2);

    prep_all_k<<<9312, 256, 0, stream>>>(x, Ws, W_out, xb, WT, WoT);
    prep_adj_k<<<1024, 256, 0, stream>>>(adj, adjp, FM1u, FM2u);

    gemm1_k<<<dim3(64, 8), 256, 0, stream>>>(xb, WT, a_s, Bp1, f1L, f2L, FM1u);
    attn1_k<<<dim3(64, 8), 512, 0, stream>>>(Bp1, adjp, f1L, f2L, FM1u, x2b);

    gemm2_k<<<64, 256, 0, stream>>>(x2b, WoT, a_out, Bp2, f12, f22, FM2u);
    attn2_k<<<dim3(64, 8), 256, 0, stream>>>(Bp2, adjp, f12, f22, FM2u, Pa2);
    attn2fin_k<<<1024, 256, 0, stream>>>(Pa2, out);
}

// Round 6
// 207.277 us; speedup vs baseline: 1.9766x; 1.1255x over previous
//
#include <hip/hip_runtime.h>
#include <hip/hip_bf16.h>
#include <stdint.h>

#define NN 4096      // nodes
#define NF 512       // NFEAT = NHEADS*NHID
#define NH 64        // NHID
#define NCLS 40      // NCLASS
#define NHEADS 8
#define LOG2E 1.4426950408889634f

typedef __attribute__((ext_vector_type(8))) short bh8;
typedef __attribute__((ext_vector_type(4))) float f32x4;

__device__ __forceinline__ unsigned short f2bu(float f) {
    union { float f; unsigned u; } v; v.f = f;
    unsigned r = (v.u + 0x7FFFu + ((v.u >> 16) & 1u)) >> 16;
    return (unsigned short)r;
}
__device__ __forceinline__ float lrelu(float x) { return fmaxf(x, 0.2f * x); }
__device__ __forceinline__ float elu1(float x) { return x > 0.f ? x : expm1f(x); }
__device__ __forceinline__ float exp2fast(float x) {
    float r; asm("v_exp_f32 %0, %1" : "=v"(r) : "v"(x)); return r;
}
// ordered-uint encode/decode for float atomicMax
__device__ __forceinline__ unsigned fenc(float f) {
    unsigned u = __builtin_bit_cast(unsigned, f);
    return ((int)u < 0) ? ~u : (u | 0x80000000u);
}
__device__ __forceinline__ float fdec(unsigned k) {
    unsigned u = (k & 0x80000000u) ? (k ^ 0x80000000u) : ~k;
    return __builtin_bit_cast(float, u);
}
// 1-bit sign-extended field extract: 0 or 0xFFFFFFFF
__device__ __forceinline__ int sbfe1(unsigned v, int off) {
#if __has_builtin(__builtin_amdgcn_sbfe)
    return __builtin_amdgcn_sbfe((int)v, off, 1);
#else
    return ((int)(v << (31 - off))) >> 31;
#endif
}
__device__ __forceinline__ float bmask(float p, unsigned mdw, int bit) {
    return __builtin_bit_cast(float,
        __builtin_bit_cast(unsigned, p) & (unsigned)sbfe1(mdw, bit));
}
// pack two f32 -> bf16 pair (RN)
__device__ __forceinline__ unsigned pack2(float x, float y) {
    unsigned ux = __builtin_bit_cast(unsigned, x), uy = __builtin_bit_cast(unsigned, y);
    ux += 0x7FFFu + ((ux >> 16) & 1u);
    uy += 0x7FFFu + ((uy >> 16) & 1u);
    return __builtin_amdgcn_perm(uy, ux, 0x07060302u);
}

// ---------------- fused prep: adj bitplanes + x/W bf16 conversion + FM init ----------------
// blocks [0,8192): adj (half-row each); [8192,10240): xb vec; [10240,11264): WT; [11264,11360): WoT
__global__ __launch_bounds__(256) void prep_all_k(const float* __restrict__ x,
                                                  const float* __restrict__ adj,
                                                  const float* __restrict__ Ws,
                                                  const float* __restrict__ Wo,
                                                  unsigned short* __restrict__ xb,
                                                  unsigned short* __restrict__ WT,
                                                  unsigned short* __restrict__ WoT,
                                                  unsigned char* __restrict__ adjp,
                                                  unsigned* __restrict__ FM1u,
                                                  unsigned* __restrict__ FM2u) {
    const int bid = blockIdx.x, tid = threadIdx.x;
    if (bid < 8192) {
        __shared__ unsigned char sm[4][64];
        const int i = bid >> 1, half = bid & 1;
        const float* rp = adj + (size_t)i * NN + half * 2048 + tid * 8;
        float4 v0 = ((const float4*)rp)[0];
        float4 v1 = ((const float4*)rp)[1];
        unsigned b = (v0.x > 0.f ? 1u : 0u) | (v0.y > 0.f ? 2u : 0u) |
                     (v0.z > 0.f ? 4u : 0u) | (v0.w > 0.f ? 8u : 0u) |
                     (v1.x > 0.f ? 16u : 0u) | (v1.y > 0.f ? 32u : 0u) |
                     (v1.z > 0.f ? 64u : 0u) | (v1.w > 0.f ? 128u : 0u);
        sm[tid & 3][tid >> 2] = (unsigned char)b;
        __syncthreads();
        if (tid < 64) {
            int gp = tid >> 4, word = tid & 15;
            unsigned d = *(const unsigned*)&sm[gp][word * 4];
            *(unsigned*)(adjp + ((size_t)i * 4 + gp) * 128 + half * 64 + word * 4) = d;
        }
    } else if (bid < 10240) {
        if (bid == 8192) {
            if (tid < 8) FM1u[tid] = 0u;
            if (tid == 8) FM2u[0] = 0u;
        }
        int t = (bid - 8192) * 256 + tid;
        float4 v = ((const float4*)x)[t];
        uint2 o; o.x = pack2(v.x, v.y); o.y = pack2(v.z, v.w);
        ((uint2*)xb)[t] = o;
    } else if (bid < 11264) {
        int j = (bid - 10240) * 256 + tid;
        int c = j >> 9, k = j & 511;
        WT[j] = f2bu(Ws[(size_t)(c >> 6) * (NF * NH) + (size_t)k * NH + (c & 63)]);
    } else {
        int j = (bid - 11264) * 256 + tid;
        int c = j >> 9, k = j & 511;
        WoT[j] = f2bu(c < NCLS ? Wo[(size_t)k * NCLS + c] : 0.f);
    }
}

// ---------------- GEMM1 (BM=128, 8 waves): Bp1 = pack(x @ Wcat), f1/f2 + FM1 ----------------
__global__ __launch_bounds__(512) void gemm1_k(const unsigned short* __restrict__ xb,
                                               const unsigned short* __restrict__ WT,
                                               const float* __restrict__ a_s,
                                               unsigned short* __restrict__ Bp1,
                                               float* __restrict__ f1L,
                                               float* __restrict__ f2L,
                                               unsigned* __restrict__ FM1u) {
    __shared__ unsigned short xs[128 * 40];
    __shared__ unsigned short wsm[64 * 40];
    const int tid = threadIdx.x;
    const int w = tid >> 6, lane = tid & 63, r16 = lane & 15, grp = lane >> 4;
    const int i0 = blockIdx.x << 7, h = blockIdx.y, c0 = h << 6;
    const int srow = tid >> 2, sseg = tid & 3;
    const unsigned short* xsrc = xb + (size_t)(i0 + srow) * NF + sseg * 8;
    const unsigned short* wsrc = WT + (size_t)(c0 + (srow & 63)) * NF + sseg * 8;
    f32x4 a0 = {0,0,0,0}, a1 = {0,0,0,0}, a2 = {0,0,0,0}, a3 = {0,0,0,0};
    bh8 rx = *(const bh8*)(xsrc);
    bh8 rw; if (tid < 256) rw = *(const bh8*)(wsrc);
    for (int kb = 0; kb < NF; kb += 32) {
        *(bh8*)(xs + srow * 40 + sseg * 8) = rx;
        if (tid < 256) *(bh8*)(wsm + srow * 40 + sseg * 8) = rw;
        __syncthreads();
        if (kb + 32 < NF) {
            rx = *(const bh8*)(xsrc + kb + 32);
            if (tid < 256) rw = *(const bh8*)(wsrc + kb + 32);
        }
        bh8 af = *(const bh8*)(xs + (w * 16 + r16) * 40 + grp * 8);
        bh8 b0 = *(const bh8*)(wsm + (r16) * 40 + grp * 8);
        bh8 b1 = *(const bh8*)(wsm + (16 + r16) * 40 + grp * 8);
        bh8 b2 = *(const bh8*)(wsm + (32 + r16) * 40 + grp * 8);
        bh8 b3 = *(const bh8*)(wsm + (48 + r16) * 40 + grp * 8);
        a0 = __builtin_amdgcn_mfma_f32_16x16x32_bf16(af, b0, a0, 0, 0, 0);
        a1 = __builtin_amdgcn_mfma_f32_16x16x32_bf16(af, b1, a1, 0, 0, 0);
        a2 = __builtin_amdgcn_mfma_f32_16x16x32_bf16(af, b2, a2, 0, 0, 0);
        a3 = __builtin_amdgcn_mfma_f32_16x16x32_bf16(af, b3, a3, 0, 0, 0);
        __syncthreads();
    }
    // direct B-panel write
    const int jt = (i0 >> 5) + (w >> 1);
    const int kg = ((w & 1) << 1) + (grp >> 1);
    const int lanep = kg * 16 + r16;
    const int ebase = (grp & 1) * 4;
    unsigned short* bp = Bp1 + ((size_t)(h * 128 + jt)) * 2048 + lanep * 8 + ebase;
    {
        uint2 v;
        v.x = pack2(a0[0], a0[1]); v.y = pack2(a0[2], a0[3]); *(uint2*)(bp + 0 * 512) = v;
        v.x = pack2(a1[0], a1[1]); v.y = pack2(a1[2], a1[3]); *(uint2*)(bp + 1 * 512) = v;
        v.x = pack2(a2[0], a2[1]); v.y = pack2(a2[2], a2[3]); *(uint2*)(bp + 2 * 512) = v;
        v.x = pack2(a3[0], a3[1]); v.y = pack2(a3[2], a3[3]); *(uint2*)(bp + 3 * 512) = v;
    }
    const float* ap = a_s + h * 128;
    float a1v[4], a2v[4];
#pragma unroll
    for (int n = 0; n < 4; ++n) { a1v[n] = ap[r16 + 16 * n]; a2v[n] = ap[64 + r16 + 16 * n]; }
    float wmax = -3.0e38f;
#pragma unroll
    for (int r = 0; r < 4; ++r) {
        const int orow = i0 + w * 16 + grp * 4 + r;
        float s1 = a0[r] * a1v[0] + a1[r] * a1v[1] + a2[r] * a1v[2] + a3[r] * a1v[3];
        float s2 = a0[r] * a2v[0] + a1[r] * a2v[1] + a2[r] * a2v[2] + a3[r] * a2v[3];
#pragma unroll
        for (int o2 = 1; o2 < 16; o2 <<= 1) { s1 += __shfl_xor(s1, o2); s2 += __shfl_xor(s2, o2); }
        s1 *= LOG2E; s2 *= LOG2E;
        if (r16 == 0) { f1L[h * NN + orow] = s1; f2L[h * NN + orow] = s2; }
        wmax = fmaxf(wmax, s2);
    }
    wmax = fmaxf(wmax, __shfl_xor(wmax, 16));
    wmax = fmaxf(wmax, __shfl_xor(wmax, 32));
    if (lane == 0) atomicMax(&FM1u[h], fenc(wmax));
}

// ---------------- GEMM2: Bp2 = pack(x2 @ W_out), f12/f22 + FM2 ----------------
__global__ __launch_bounds__(256) void gemm2_k(const unsigned short* __restrict__ x2b,
                                               const unsigned short* __restrict__ WoT,
                                               const float* __restrict__ a_out,
                                               unsigned short* __restrict__ Bp2,
                                               float* __restrict__ f12L,
                                               float* __restrict__ f22L,
                                               unsigned* __restrict__ FM2u) {
    __shared__ unsigned short xs[64 * 40];
    __shared__ unsigned short wsm[48 * 40];
    const int tid = threadIdx.x;
    const int w = tid >> 6, lane = tid & 63, r16 = lane & 15, grp = lane >> 4;
    const int i0 = blockIdx.x << 6;
    const int srow = tid >> 2, sseg = tid & 3;
    const unsigned short* xsrc = x2b + (size_t)(i0 + srow) * NF + sseg * 8;
    const unsigned short* wsrc = WoT + (size_t)srow * NF + sseg * 8;
    f32x4 a0 = {0,0,0,0}, a1 = {0,0,0,0}, a2 = {0,0,0,0};
    bh8 rx = *(const bh8*)(xsrc);
    bh8 rw; if (tid < 192) rw = *(const bh8*)(wsrc);
    for (int kb = 0; kb < NF; kb += 32) {
        *(bh8*)(xs + srow * 40 + sseg * 8) = rx;
        if (tid < 192) *(bh8*)(wsm + srow * 40 + sseg * 8) = rw;
        __syncthreads();
        if (kb + 32 < NF) {
            rx = *(const bh8*)(xsrc + kb + 32);
            if (tid < 192) rw = *(const bh8*)(wsrc + kb + 32);
        }
        bh8 af = *(const bh8*)(xs + (w * 16 + r16) * 40 + grp * 8);
        bh8 b0 = *(const bh8*)(wsm + (r16) * 40 + grp * 8);
        bh8 b1 = *(const bh8*)(wsm + (16 + r16) * 40 + grp * 8);
        bh8 b2 = *(const bh8*)(wsm + (32 + r16) * 40 + grp * 8);
        a0 = __builtin_amdgcn_mfma_f32_16x16x32_bf16(af, b0, a0, 0, 0, 0);
        a1 = __builtin_amdgcn_mfma_f32_16x16x32_bf16(af, b1, a1, 0, 0, 0);
        a2 = __builtin_amdgcn_mfma_f32_16x16x32_bf16(af, b2, a2, 0, 0, 0);
        __syncthreads();
    }
    const int jt = (i0 >> 5) + (w >> 1);
    const int kg = ((w & 1) << 1) + (grp >> 1);
    const int lanep = kg * 16 + r16;
    const int ebase = (grp & 1) * 4;
    unsigned short* bp = Bp2 + (size_t)jt * 1536 + lanep * 8 + ebase;
    {
        uint2 v;
        v.x = pack2(a0[0], a0[1]); v.y = pack2(a0[2], a0[3]); *(uint2*)(bp + 0 * 512) = v;
        v.x = pack2(a1[0], a1[1]); v.y = pack2(a1[2], a1[3]); *(uint2*)(bp + 1 * 512) = v;
        v.x = pack2(a2[0], a2[1]); v.y = pack2(a2[2], a2[3]); *(uint2*)(bp + 2 * 512) = v;
    }
    float a1v[3], a2v[3];
#pragma unroll
    for (int n = 0; n < 3; ++n) {
        int col = r16 + 16 * n;
        a1v[n] = col < NCLS ? a_out[col] : 0.f;
        a2v[n] = col < NCLS ? a_out[NCLS + col] : 0.f;
    }
    float wmax = -3.0e38f;
#pragma unroll
    for (int r = 0; r < 4; ++r) {
        const int orow = i0 + w * 16 + grp * 4 + r;
        float s1 = a0[r] * a1v[0] + a1[r] * a1v[1] + a2[r] * a1v[2];
        float s2 = a0[r] * a2v[0] + a1[r] * a2v[1] + a2[r] * a2v[2];
#pragma unroll
        for (int o2 = 1; o2 < 16; o2 <<= 1) { s1 += __shfl_xor(s1, o2); s2 += __shfl_xor(s2, o2); }
        s1 *= LOG2E; s2 *= LOG2E;
        if (r16 == 0) { f12L[orow] = s1; f22L[orow] = s2; }
        wmax = fmaxf(wmax, s2);
    }
    wmax = fmaxf(wmax, __shfl_xor(wmax, 16));
    wmax = fmaxf(wmax, __shfl_xor(wmax, 32));
    if (lane == 0) atomicMax(&FM2u[0], fenc(wmax));
}

// ---------------- attn layer 1: EF tables in LDS, adj via registers ----------------
__global__ __launch_bounds__(512, 6) void attn1_k(const unsigned short* __restrict__ Bp1,
                                                  const unsigned char* __restrict__ adjp,
                                                  const float* __restrict__ f1L,
                                                  const float* __restrict__ f2L,
                                                  const unsigned* __restrict__ FM1u,
                                                  unsigned short* __restrict__ x2b) {
    __shared__ float EFs[8192];                 // 32 KiB (reused as comb)
    const int tid = threadIdx.x, w = tid >> 6, lane = tid & 63;
    const int r16 = lane & 15, grp = lane >> 4;
    const int rowg = w & 3, jq = w >> 2;
    const int h = blockIdx.y;
    const int i0 = blockIdx.x * 64;
    const float fm = fdec(FM1u[h]);
    const float* f2p = f2L + h * NN;
    for (int t = 0; t < 8; ++t) {
        int j = tid + t * 512;
        float d = f2p[j] - fm;
        EFs[2 * j] = exp2fast(d);
        EFs[2 * j + 1] = exp2fast(0.2f * d);
    }
    const int irow = i0 + rowg * 16 + r16;
    const float f1v = f1L[h * NN + irow];
    const float mL = lrelu(f1v + fm);
    const float A = exp2fast(f1v + fm - mL);
    const float B = exp2fast(__builtin_fmaf(0.2f, f1v + fm, -mL));
    __syncthreads();
    const int jtbase = jq * 64;
    const unsigned char* adjr = adjp + ((size_t)irow * 4 + grp) * 128 + jtbase;
    const float* efp = EFs + grp * 16;
    const unsigned short* Bbase = Bp1 + (size_t)h * 128 * 2048 + lane * 8;
    f32x4 acc0 = {0,0,0,0}, acc1 = {0,0,0,0}, acc2 = {0,0,0,0}, acc3 = {0,0,0,0}, accd = {0,0,0,0};
    const short ov = (r16 == 0) ? (short)0x3F80 : (short)0;
    bh8 ones;
#pragma unroll
    for (int e = 0; e < 8; ++e) ones[e] = ov;
    bh8 nb0, nb1, nb2, nb3;
#define PREF1(JT) { const unsigned short* Bn = Bbase + (size_t)(JT) * 2048;              \
        nb0 = *(const bh8*)(Bn);        nb1 = *(const bh8*)(Bn + 512);                    \
        nb2 = *(const bh8*)(Bn + 1024); nb3 = *(const bh8*)(Bn + 1536); }
    PREF1(jtbase);
    for (int jt16 = 0; jt16 < 4; ++jt16) {
        const uint4 a4 = *(const uint4*)(adjr + jt16 * 16);
#pragma unroll
        for (int q = 0; q < 4; ++q) {
            const unsigned mdw = (q == 0) ? a4.x : (q == 1) ? a4.y : (q == 2) ? a4.z : a4.w;
#pragma unroll
            for (int u = 0; u < 4; ++u) {
                const int jt = jtbase + jt16 * 16 + q * 4 + u;
                bh8 b0 = nb0, b1 = nb1, b2 = nb2, b3 = nb3;
                PREF1(jt + 1);
                const float* e4 = efp + jt * 64;
                float4 ea = *(const float4*)(e4);
                float4 eb = *(const float4*)(e4 + 4);
                float4 ec = *(const float4*)(e4 + 8);
                float4 ed = *(const float4*)(e4 + 12);
                const int bb = u * 8;
                union { bh8 v; unsigned u32[4]; } pk;
                {
                    float p0 = bmask(fmaxf(A * ea.x, B * ea.y), mdw, bb + 0);
                    float p1 = bmask(fmaxf(A * ea.z, B * ea.w), mdw, bb + 1);
                    pk.u32[0] = __builtin_amdgcn_perm(__builtin_bit_cast(unsigned, p1),
                                                      __builtin_bit_cast(unsigned, p0), 0x07060302u);
                    float p2 = bmask(fmaxf(A * eb.x, B * eb.y), mdw, bb + 2);
                    float p3 = bmask(fmaxf(A * eb.z, B * eb.w), mdw, bb + 3);
                    pk.u32[1] = __builtin_amdgcn_perm(__builtin_bit_cast(unsigned, p3),
                                                      __builtin_bit_cast(unsigned, p2), 0x07060302u);
                    float p4 = bmask(fmaxf(A * ec.x, B * ec.y), mdw, bb + 4);
                    float p5 = bmask(fmaxf(A * ec.z, B * ec.w), mdw, bb + 5);
                    pk.u32[2] = __builtin_amdgcn_perm(__builtin_bit_cast(unsigned, p5),
                                                      __builtin_bit_cast(unsigned, p4), 0x07060302u);
                    float p6 = bmask(fmaxf(A * ed.x, B * ed.y), mdw, bb + 6);
                    float p7 = bmask(fmaxf(A * ed.z, B * ed.w), mdw, bb + 7);
                    pk.u32[3] = __builtin_amdgcn_perm(__builtin_bit_cast(unsigned, p7),
                                                      __builtin_bit_cast(unsigned, p6), 0x07060302u);
                }
                acc0 = __builtin_amdgcn_mfma_f32_16x16x32_bf16(pk.v, b0, acc0, 0, 0, 0);
                acc1 = __builtin_amdgcn_mfma_f32_16x16x32_bf16(pk.v, b1, acc1, 0, 0, 0);
                acc2 = __builtin_amdgcn_mfma_f32_16x16x32_bf16(pk.v, b2, acc2, 0, 0, 0);
                acc3 = __builtin_amdgcn_mfma_f32_16x16x32_bf16(pk.v, b3, acc3, 0, 0, 0);
                accd = __builtin_amdgcn_mfma_f32_16x16x32_bf16(pk.v, ones, accd, 0, 0, 0);
            }
        }
    }
#undef PREF1
    __syncthreads();                 // done reading EFs
    float (*comb)[64][21] = (float(*)[64][21])EFs;   // 21-pad: conflict-free
    if (jq == 1) {
        float* cb = &comb[rowg][lane][0];
#pragma unroll
        for (int r = 0; r < 4; ++r) {
            cb[r] = acc0[r]; cb[4 + r] = acc1[r]; cb[8 + r] = acc2[r];
            cb[12 + r] = acc3[r]; cb[16 + r] = accd[r];
        }
    }
    __syncthreads();
    if (jq == 0) {
        const float* cb = &comb[rowg][lane][0];
#pragma unroll
        for (int r = 0; r < 4; ++r) {
            acc0[r] += cb[r]; acc1[r] += cb[4 + r]; acc2[r] += cb[8 + r];
            acc3[r] += cb[12 + r]; accd[r] += cb[16 + r];
        }
#pragma unroll
        for (int r = 0; r < 4; ++r) {
            const float den = __shfl(accd[r], lane & 48);
            const float inv = 1.0f / den;
            unsigned short* o = x2b + (size_t)(i0 + rowg * 16 + grp * 4 + r) * NF + h * 64 + r16;
            o[0]  = f2bu(elu1(acc0[r] * inv));
            o[16] = f2bu(elu1(acc1[r] * inv));
            o[32] = f2bu(elu1(acc2[r] * inv));
            o[48] = f2bu(elu1(acc3[r] * inv));
        }
    }
}

// ---------------- attn layer 2: single pass, fused elu + log_softmax ----------------
// block = 16 rows x all 4096 j; 8 waves split j 8-way; LDS tree combine
__global__ __launch_bounds__(512, 6) void attn2_k(const unsigned short* __restrict__ Bp2,
                                                  const unsigned char* __restrict__ adjp,
                                                  const float* __restrict__ f12L,
                                                  const float* __restrict__ f22L,
                                                  const unsigned* __restrict__ FM2u,
                                                  float* __restrict__ out) {
    __shared__ float EFs[8192];          // 32 KiB
    __shared__ float comb[8][64][17];    // 34.8 KiB
    const int tid = threadIdx.x, w = tid >> 6, lane = tid & 63;
    const int r16 = lane & 15, grp = lane >> 4;
    const int i0 = blockIdx.x * 16;
    const int i = i0 + r16;
    const float fm = fdec(FM2u[0]);
    for (int t = 0; t < 8; ++t) {
        int j = tid + t * 512;
        float d = f22L[j] - fm;
        EFs[2 * j] = exp2fast(d);
        EFs[2 * j + 1] = exp2fast(0.2f * d);
    }
    const float f1v = f12L[i];
    const float mL = lrelu(f1v + fm);
    const float A = exp2fast(f1v + fm - mL);
    const float B = exp2fast(__builtin_fmaf(0.2f, f1v + fm, -mL));
    __syncthreads();
    const int jt0 = w * 16;
    const uint4 a4 = *(const uint4*)(adjp + ((size_t)i * 4 + grp) * 128 + jt0);
    f32x4 acc0 = {0,0,0,0}, acc1 = {0,0,0,0}, acc2 = {0,0,0,0}, accd = {0,0,0,0};
    const short ov = (r16 == 0) ? (short)0x3F80 : (short)0;
    bh8 ones;
#pragma unroll
    for (int e = 0; e < 8; ++e) ones[e] = ov;
    const unsigned short* Bbase = Bp2 + lane * 8;
    const float* efp = EFs + grp * 16;
    bh8 nb0, nb1, nb2;
#define PREF2(JT) { const unsigned short* Bn = Bbase + (size_t)(JT) * 1536;              \
        nb0 = *(const bh8*)(Bn); nb1 = *(const bh8*)(Bn + 512); nb2 = *(const bh8*)(Bn + 1024); }
    PREF2(jt0);
#pragma unroll
    for (int q = 0; q < 4; ++q) {
        const unsigned mdw = (q == 0) ? a4.x : (q == 1) ? a4.y : (q == 2) ? a4.z : a4.w;
#pragma unroll
        for (int u = 0; u < 4; ++u) {
            const int jt = jt0 + q * 4 + u;
            bh8 b0 = nb0, b1 = nb1, b2 = nb2;
            PREF2(jt + 1);
            const float* e4 = efp + jt * 64;
            float4 ea = *(const float4*)(e4);
            float4 eb = *(const float4*)(e4 + 4);
            float4 ec = *(const float4*)(e4 + 8);
            float4 ed = *(const float4*)(e4 + 12);
            const int bb = u * 8;
            union { bh8 v; unsigned u32[4]; } pk;
            {
                float p0 = bmask(fmaxf(A * ea.x, B * ea.y), mdw, bb + 0);
                float p1 = bmask(fmaxf(A * ea.z, B * ea.w), mdw, bb + 1);
                pk.u32[0] = __builtin_amdgcn_perm(__builtin_bit_cast(unsigned, p1),
                                                  __builtin_bit_cast(unsigned, p0), 0x07060302u);
                float p2 = bmask(fmaxf(A * eb.x, B * eb.y), mdw, bb + 2);
                float p3 = bmask(fmaxf(A * eb.z, B * eb.w), mdw, bb + 3);
                pk.u32[1] = __builtin_amdgcn_perm(__builtin_bit_cast(unsigned, p3),
                                                  __builtin_bit_cast(unsigned, p2), 0x07060302u);
                float p4 = bmask(fmaxf(A * ec.x, B * ec.y), mdw, bb + 4);
                float p5 = bmask(fmaxf(A * ec.z, B * ec.w), mdw, bb + 5);
                pk.u32[2] = __builtin_amdgcn_perm(__builtin_bit_cast(unsigned, p5),
                                                  __builtin_bit_cast(unsigned, p4), 0x07060302u);
                float p6 = bmask(fmaxf(A * ed.x, B * ed.y), mdw, bb + 6);
                float p7 = bmask(fmaxf(A * ed.z, B * ed.w), mdw, bb + 7);
                pk.u32[3] = __builtin_amdgcn_perm(__builtin_bit_cast(unsigned, p7),
                                                  __builtin_bit_cast(unsigned, p6), 0x07060302u);
            }
            acc0 = __builtin_amdgcn_mfma_f32_16x16x32_bf16(pk.v, b0, acc0, 0, 0, 0);
            acc1 = __builtin_amdgcn_mfma_f32_16x16x32_bf16(pk.v, b1, acc1, 0, 0, 0);
            acc2 = __builtin_amdgcn_mfma_f32_16x16x32_bf16(pk.v, b2, acc2, 0, 0, 0);
            accd = __builtin_amdgcn_mfma_f32_16x16x32_bf16(pk.v, ones, accd, 0, 0, 0);
        }
    }
#undef PREF2
    // tree combine over 8 waves
    {
        float* cb = &comb[w][lane][0];
#pragma unroll
        for (int r = 0; r < 4; ++r) {
            cb[r] = acc0[r]; cb[4 + r] = acc1[r]; cb[8 + r] = acc2[r]; cb[12 + r] = accd[r];
        }
    }
    __syncthreads();
    if (w < 4) {
        const float* sb = &comb[w + 4][lane][0];
        float* cb = &comb[w][lane][0];
#pragma unroll
        for (int r = 0; r < 4; ++r) {
            acc0[r] += sb[r]; acc1[r] += sb[4 + r]; acc2[r] += sb[8 + r]; accd[r] += sb[12 + r];
            cb[r] = acc0[r]; cb[4 + r] = acc1[r]; cb[8 + r] = acc2[r]; cb[12 + r] = accd[r];
        }
    }
    __syncthreads();
    if (w < 2) {
        const float* sb = &comb[w + 2][lane][0];
        float* cb = &comb[w][lane][0];
#pragma unroll
        for (int r = 0; r < 4; ++r) {
            acc0[r] += sb[r]; acc1[r] += sb[4 + r]; acc2[r] += sb[8 + r]; accd[r] += sb[12 + r];
            cb[r] = acc0[r]; cb[4 + r] = acc1[r]; cb[8 + r] = acc2[r]; cb[12 + r] = accd[r];
        }
    }
    __syncthreads();
    if (w == 0) {
        const float* sb = &comb[1][lane][0];
#pragma unroll
        for (int r = 0; r < 4; ++r) {
            acc0[r] += sb[r]; acc1[r] += sb[4 + r]; acc2[r] += sb[8 + r]; accd[r] += sb[12 + r];
        }
        // finish: denom, elu, log_softmax, write
#pragma unroll
        for (int r = 0; r < 4; ++r) {
            const int row = grp * 4 + r;
            const float den = __shfl(accd[r], lane & 48);
            const float inv = 1.0f / den;
            float v0 = elu1(acc0[r] * inv);
            float v1 = elu1(acc1[r] * inv);
            float v2 = (r16 < 8) ? elu1(acc2[r] * inv) : -3.0e38f;
            float mx = fmaxf(fmaxf(v0, v1), v2);
#pragma unroll
            for (int o = 1; o < 16; o <<= 1) mx = fmaxf(mx, __shfl_xor(mx, o));
            float ex = __expf(v0 - mx) + __expf(v1 - mx) + ((r16 < 8) ? __expf(v2 - mx) : 0.f);
#pragma unroll
            for (int o = 1; o < 16; o <<= 1) ex += __shfl_xor(ex, o);
            const float lse = mx + logf(ex);
            float* op = out + (size_t)(i0 + row) * NCLS;
            op[r16] = v0 - lse;
            op[16 + r16] = v1 - lse;
            if (r16 < 8) op[32 + r16] = v2 - lse;
        }
    }
}

// ---------------- workspace layout (bytes) ----------------
#define OFF_XB   0ULL           // 4096*512*2 = 4194304
#define OFF_WT   4194304ULL     // 512*512*2  = 524288
#define OFF_WOT  4718592ULL     // 48*512*2   = 49152
#define OFF_BP1  4767744ULL     // 8*128*2048*2 = 4194304
#define OFF_X2B  8962048ULL     // 4096*512*2 = 4194304
#define OFF_BP2  13156352ULL    // 128*1536*2 = 393216
#define OFF_F1L  13549568ULL    // 8*4096*4 = 131072
#define OFF_F2L  13680640ULL    // 131072
#define OFF_F12  13811712ULL    // 16384
#define OFF_F22  13828096ULL    // 16384
#define OFF_FM1  13844480ULL    // 256
#define OFF_FM2  13844736ULL    // 256
#define OFF_ADJ  13844992ULL    // 4096*4*128 = 2097152 -> end 15942144

extern "C" void kernel_launch(void* const* d_in, const int* in_sizes, int n_in,
                              void* d_out, int out_size, void* d_ws, size_t ws_size,
                              hipStream_t stream) {
    const float* x     = (const float*)d_in[0];
    const float* adj   = (const float*)d_in[1];
    const float* Ws    = (const float*)d_in[2];
    const float* a_s   = (const float*)d_in[3];
    const float* W_out = (const float*)d_in[4];
    const float* a_out = (const float*)d_in[5];
    float* out = (float*)d_out;
    char* w = (char*)d_ws;

    unsigned short* xb  = (unsigned short*)(w + OFF_XB);
    unsigned short* WT  = (unsigned short*)(w + OFF_WT);
    unsigned short* WoT = (unsigned short*)(w + OFF_WOT);
    unsigned short* Bp1 = (unsigned short*)(w + OFF_BP1);
    unsigned short* x2b = (unsigned short*)(w + OFF_X2B);
    unsigned short* Bp2 = (unsigned short*)(w + OFF_BP2);
    float* f1L = (float*)(w + OFF_F1L);
    float* f2L = (float*)(w + OFF_F2L);
    float* f12 = (float*)(w + OFF_F12);
    float* f22 = (float*)(w + OFF_F22);
    unsigned* FM1u = (unsigned*)(w + OFF_FM1);
    unsigned* FM2u = (unsigned*)(w + OFF_FM2);
    unsigned char* adjp = (unsigned char*)(w + OFF_ADJ);

    prep_all_k<<<11360, 256, 0, stream>>>(x, adj, Ws, W_out, xb, WT, WoT, adjp, FM1u, FM2u);
    gemm1_k<<<dim3(32, 8), 512, 0, stream>>>(xb, WT, a_s, Bp1, f1L, f2L, FM1u);
    attn1_k<<<dim3(64, 8), 512, 0, stream>>>(Bp1, adjp, f1L, f2L, FM1u, x2b);
    gemm2_k<<<64, 256, 0, stream>>>(x2b, WoT, a_out, Bp2, f12, f22, FM2u);
    attn2_k<<<256, 512, 0, stream>>>(Bp2, adjp, f12, f22, FM2u, out);
}